// Round 1
// baseline (1599.904 us; speedup 1.0000x reference)
//
#include <hip/hip_runtime.h>

#define NEG_SLOPE 0.2f
#define EPSF 1e-16f

// Monotonic float<->uint mapping for atomicMax on floats.
__device__ __forceinline__ unsigned int fmap(float f) {
    unsigned int b = __float_as_uint(f);
    return (b & 0x80000000u) ? ~b : (b | 0x80000000u);
}
__device__ __forceinline__ float funmap(unsigned int u) {
    unsigned int b = (u & 0x80000000u) ? (u ^ 0x80000000u) : ~u;
    return __uint_as_float(b);
}

// h = X[N,128] @ W[128,COLS], X row stride fixed at 128.
template<int COLS>
__global__ __launch_bounds__(256) void gemm128(const float* __restrict__ X,
                                               const float* __restrict__ W,
                                               float* __restrict__ Out, int N) {
    __shared__ float Xs[32][128];
    __shared__ float Ws[128][COLS];
    const int tid = threadIdx.x;
    const int row0 = blockIdx.x * 32;
    for (int i = tid; i < 128 * COLS; i += 256)
        Ws[i / COLS][i % COLS] = W[i];
    for (int i = tid; i < 32 * 128; i += 256) {
        int r = i >> 7, c = i & 127;
        int gr = row0 + r;
        Xs[r][c] = (gr < N) ? X[(size_t)gr * 128 + c] : 0.f;
    }
    __syncthreads();
    constexpr int RPT = 32 * COLS / 256;  // 16 for COLS=128, 8 for COLS=64
    const int col = tid % COLS;
    const int rb = (tid / COLS) * RPT;
    float acc[RPT];
#pragma unroll
    for (int r = 0; r < RPT; ++r) acc[r] = 0.f;
    for (int k = 0; k < 128; ++k) {
        float w = Ws[k][col];
#pragma unroll
        for (int r = 0; r < RPT; ++r) acc[r] = fmaf(Xs[rb + r][k], w, acc[r]);
    }
#pragma unroll
    for (int r = 0; r < RPT; ++r) {
        int gr = row0 + rb + r;
        if (gr < N) Out[(size_t)gr * COLS + col] = acc[r];
    }
}

// alpha_s[n,h] = dot(h[n,h,:], a_src[h,:]); same for alpha_d. One wave per node.
__global__ void alphas_kernel(const float* __restrict__ H, const float* __restrict__ a_s,
                              const float* __restrict__ a_d, float* __restrict__ AS,
                              float* __restrict__ AD, int N, int HEADS) {
    const int lane = threadIdx.x & 63;
    const int wid = (int)((blockIdx.x * blockDim.x + threadIdx.x) >> 6);
    const int nw = (int)((gridDim.x * blockDim.x) >> 6);
    const int HC = HEADS * 64;
    for (int n = wid; n < N; n += nw) {
        for (int h = 0; h < HEADS; ++h) {
            float v = H[(size_t)n * HC + h * 64 + lane];
            float s = v * a_s[h * 64 + lane];
            float d = v * a_d[h * 64 + lane];
            for (int o = 32; o > 0; o >>= 1) {
                s += __shfl_down(s, o, 64);
                d += __shfl_down(d, o, 64);
            }
            if (lane == 0) { AS[n * HEADS + h] = s; AD[n * HEADS + h] = d; }
        }
    }
}

// Pass A: e = leaky_relu(as[src]+ad[dst]); store; atomicMax mapped into Mb[dst].
__global__ void edge_logits(const int* __restrict__ ei, int E_raw, int N,
                            const float* __restrict__ AS, const float* __restrict__ AD,
                            float* __restrict__ Eb, unsigned int* __restrict__ Mb, int HEADS) {
    const int E = E_raw + N;
    for (int e = blockIdx.x * blockDim.x + threadIdx.x; e < E; e += gridDim.x * blockDim.x) {
        int s, d;
        if (e < E_raw) { s = ei[e]; d = ei[E_raw + e]; } else { s = d = e - E_raw; }
        for (int h = 0; h < HEADS; ++h) {
            float v = AS[s * HEADS + h] + AD[d * HEADS + h];
            v = v > 0.f ? v : NEG_SLOPE * v;
            Eb[(size_t)e * HEADS + h] = v;
            atomicMax(&Mb[d * HEADS + h], fmap(v));
        }
    }
}

__global__ void unmap_kernel(unsigned int* Mb, int total) {
    int i = blockIdx.x * blockDim.x + threadIdx.x;
    if (i < total) {
        float f = funmap(Mb[i]);
        ((float*)Mb)[i] = f;
    }
}

// Pass B: Eb = exp(Eb - m[dst]); denom[dst] += Eb.
__global__ void edge_exp(const int* __restrict__ ei, int E_raw, int N,
                         const float* __restrict__ Mf, float* __restrict__ Eb,
                         float* __restrict__ Db, int HEADS) {
    const int E = E_raw + N;
    for (int e = blockIdx.x * blockDim.x + threadIdx.x; e < E; e += gridDim.x * blockDim.x) {
        int d = (e < E_raw) ? ei[E_raw + e] : e - E_raw;
        for (int h = 0; h < HEADS; ++h) {
            float v = expf(Eb[(size_t)e * HEADS + h] - Mf[d * HEADS + h]);
            Eb[(size_t)e * HEADS + h] = v;
            unsafeAtomicAdd(&Db[d * HEADS + h], v);
        }
    }
}

// Pass C: out[dst, h, :] += (Eb / (denom+eps)) * h[src, h, :]. One wave per edge.
template<int HEADS>
__global__ void edge_aggregate(const int* __restrict__ ei, int E_raw, int N,
                               const float* __restrict__ Hsrc, const float* __restrict__ Eb,
                               const float* __restrict__ Db, float* __restrict__ Out) {
    const int E = E_raw + N;
    const int lane = threadIdx.x & 63;
    const int wid = (int)((blockIdx.x * blockDim.x + threadIdx.x) >> 6);
    const int nw = (int)((gridDim.x * blockDim.x) >> 6);
    for (int e = wid; e < E; e += nw) {
        int s, d;
        if (e < E_raw) { s = ei[e]; d = ei[E_raw + e]; } else { s = d = e - E_raw; }
#pragma unroll
        for (int h = 0; h < HEADS; ++h) {
            float alpha = Eb[(size_t)e * HEADS + h] / (Db[d * HEADS + h] + EPSF);
            float v = Hsrc[(size_t)s * (HEADS * 64) + h * 64 + lane] * alpha;
            unsafeAtomicAdd(&Out[(size_t)d * (HEADS * 64) + h * 64 + lane], v);
        }
    }
}

// out = (relu?)(out + b)
__global__ void bias_act(float* __restrict__ buf, const float* __restrict__ b,
                         int total, int HC, int do_relu) {
    int i = blockIdx.x * blockDim.x + threadIdx.x;
    if (i < total) {
        float v = buf[i] + b[i % HC];
        if (do_relu) v = fmaxf(v, 0.f);
        buf[i] = v;
    }
}

extern "C" void kernel_launch(void* const* d_in, const int* in_sizes, int n_in,
                              void* d_out, int out_size, void* d_ws, size_t ws_size,
                              hipStream_t stream) {
    const float* x   = (const float*)d_in[0];
    const int*   ei  = (const int*)d_in[1];
    const float* W0  = (const float*)d_in[2];
    const float* as0 = (const float*)d_in[3];
    const float* ad0 = (const float*)d_in[4];
    const float* b0  = (const float*)d_in[5];
    const float* W1  = (const float*)d_in[6];
    const float* as1 = (const float*)d_in[7];
    const float* ad1 = (const float*)d_in[8];
    const float* b1  = (const float*)d_in[9];
    const float* W2  = (const float*)d_in[10];
    const float* as2 = (const float*)d_in[11];
    const float* ad2 = (const float*)d_in[12];
    const float* b2  = (const float*)d_in[13];

    const int N = in_sizes[0] / 128;
    const int E_raw = in_sizes[1] / 2;
    const int E = E_raw + N;

    char* ws = (char*)d_ws;
    size_t off = 0;
    auto alloc = [&](size_t bytes) {
        void* p = ws + off;
        off = (off + bytes + 255) & ~(size_t)255;
        return p;
    };
    float* hbuf = (float*)alloc((size_t)N * 128 * 4);
    float* obuf = (float*)alloc((size_t)N * 128 * 4);
    float* asb  = (float*)alloc((size_t)N * 2 * 4);
    float* adb  = (float*)alloc((size_t)N * 2 * 4);
    unsigned int* mb = (unsigned int*)alloc((size_t)N * 2 * 4);
    float* db   = (float*)alloc((size_t)N * 2 * 4);
    float* eb   = (float*)alloc((size_t)E * 2 * 4);
    (void)ws_size; (void)n_in; (void)out_size;

    auto run_layer = [&](const float* Xin, const float* W, const float* a_s,
                         const float* a_d, const float* b, int HEADS,
                         float* Hl, float* Oout, int do_relu) {
        const int HC = HEADS * 64;
        const int gblocks = (N + 31) / 32;
        if (HC == 128) gemm128<128><<<gblocks, 256, 0, stream>>>(Xin, W, Hl, N);
        else           gemm128<64><<<gblocks, 256, 0, stream>>>(Xin, W, Hl, N);
        alphas_kernel<<<512, 256, 0, stream>>>(Hl, a_s, a_d, asb, adb, N, HEADS);
        hipMemsetAsync(mb, 0, (size_t)N * HEADS * 4, stream);
        hipMemsetAsync(db, 0, (size_t)N * HEADS * 4, stream);
        hipMemsetAsync(Oout, 0, (size_t)N * HC * 4, stream);
        edge_logits<<<1024, 256, 0, stream>>>(ei, E_raw, N, asb, adb, eb, mb, HEADS);
        unmap_kernel<<<(N * HEADS + 255) / 256, 256, 0, stream>>>(mb, N * HEADS);
        edge_exp<<<1024, 256, 0, stream>>>(ei, E_raw, N, (const float*)mb, eb, db, HEADS);
        if (HEADS == 2)
            edge_aggregate<2><<<2048, 256, 0, stream>>>(ei, E_raw, N, Hl, eb, db, Oout);
        else
            edge_aggregate<1><<<2048, 256, 0, stream>>>(ei, E_raw, N, Hl, eb, db, Oout);
        bias_act<<<((size_t)N * HC + 255) / 256, 256, 0, stream>>>(Oout, b, N * HC, HC, do_relu);
    };

    // Layer 0: x[N,128] -> obuf[N,128], relu
    run_layer(x, W0, as0, ad0, b0, 2, hbuf, obuf, 1);
    // Layer 1: obuf -> obuf (hbuf is the GEMM dest; obuf re-zeroed after GEMM reads it)
    run_layer(obuf, W1, as1, ad1, b1, 2, hbuf, obuf, 1);
    // Layer 2: obuf -> d_out (heads=1, no relu)
    run_layer(obuf, W2, as2, ad2, b2, 1, hbuf, (float*)d_out, 0);
}

// Round 2
// 523.199 us; speedup vs baseline: 3.0579x; 3.0579x over previous
//
#include <hip/hip_runtime.h>

#define NEG_SLOPE 0.2f
#define EPSF 1e-16f

// ---------- GEMM: h = X[N,128] @ W[128,COLS] ----------
template<int COLS>
__global__ __launch_bounds__(256) void gemm128(const float* __restrict__ X,
                                               const float* __restrict__ W,
                                               float* __restrict__ Out, int N) {
    __shared__ float Xs[32][128];
    __shared__ float Ws[128][COLS];
    const int tid = threadIdx.x;
    const int row0 = blockIdx.x * 32;
    for (int i = tid; i < 128 * COLS; i += 256)
        Ws[i / COLS][i % COLS] = W[i];
    for (int i = tid; i < 32 * 128; i += 256) {
        int r = i >> 7, c = i & 127;
        int gr = row0 + r;
        Xs[r][c] = (gr < N) ? X[(size_t)gr * 128 + c] : 0.f;
    }
    __syncthreads();
    constexpr int RPT = 32 * COLS / 256;
    const int col = tid % COLS;
    const int rb = (tid / COLS) * RPT;
    float acc[RPT];
#pragma unroll
    for (int r = 0; r < RPT; ++r) acc[r] = 0.f;
    for (int k = 0; k < 128; ++k) {
        float w = Ws[k][col];
#pragma unroll
        for (int r = 0; r < RPT; ++r) acc[r] = fmaf(Xs[rb + r][k], w, acc[r]);
    }
#pragma unroll
    for (int r = 0; r < RPT; ++r) {
        int gr = row0 + rb + r;
        if (gr < N) Out[(size_t)gr * COLS + col] = acc[r];
    }
}

// ---------- per-node attention coefficients ----------
__global__ void alphas_kernel(const float* __restrict__ H, const float* __restrict__ a_s,
                              const float* __restrict__ a_d, float* __restrict__ AS,
                              float* __restrict__ AD, int N, int HEADS) {
    const int lane = threadIdx.x & 63;
    const int wid = (int)((blockIdx.x * blockDim.x + threadIdx.x) >> 6);
    const int nw = (int)((gridDim.x * blockDim.x) >> 6);
    const int HC = HEADS * 64;
    for (int n = wid; n < N; n += nw) {
        for (int h = 0; h < HEADS; ++h) {
            float v = H[(size_t)n * HC + h * 64 + lane];
            float s = v * a_s[h * 64 + lane];
            float d = v * a_d[h * 64 + lane];
            for (int o = 32; o > 0; o >>= 1) {
                s += __shfl_down(s, o, 64);
                d += __shfl_down(d, o, 64);
            }
            if (lane == 0) { AS[n * HEADS + h] = s; AD[n * HEADS + h] = d; }
        }
    }
}

// ---------- CSR build: histogram, scan, scatter ----------
__global__ void hist_kernel(const int* __restrict__ ei, int E_raw, int N,
                            int* __restrict__ cnt) {
    const int E = E_raw + N;
    for (int e = blockIdx.x * blockDim.x + threadIdx.x; e < E; e += gridDim.x * blockDim.x) {
        int d = (e < E_raw) ? ei[E_raw + e] : e - E_raw;
        atomicAdd(&cnt[d], 1);
    }
}

// exclusive scan of 256 elems per block; block total -> bsum
__global__ __launch_bounds__(256) void scan_block(const int* __restrict__ cnt,
                                                  int* __restrict__ offs,
                                                  int* __restrict__ bsum, int N) {
    __shared__ int wsum[4];
    const int i = blockIdx.x * 256 + threadIdx.x;
    const int lane = threadIdx.x & 63, w = threadIdx.x >> 6;
    int v = (i < N) ? cnt[i] : 0;
    int incl = v;
    for (int o = 1; o < 64; o <<= 1) {
        int t = __shfl_up(incl, o, 64);
        if (lane >= o) incl += t;
    }
    if (lane == 63) wsum[w] = incl;
    __syncthreads();
    int prefix = 0;
    for (int k = 0; k < w; ++k) prefix += wsum[k];
    if (i < N) offs[i] = prefix + incl - v;
    if (threadIdx.x == 255) bsum[blockIdx.x] = prefix + incl;
}

// single-block exclusive scan of bsum (nb <= 256)
__global__ __launch_bounds__(256) void scan_bsum(int* __restrict__ bsum, int nb) {
    __shared__ int wsum[4];
    const int lane = threadIdx.x & 63, w = threadIdx.x >> 6;
    int v = (threadIdx.x < nb) ? bsum[threadIdx.x] : 0;
    int incl = v;
    for (int o = 1; o < 64; o <<= 1) {
        int t = __shfl_up(incl, o, 64);
        if (lane >= o) incl += t;
    }
    if (lane == 63) wsum[w] = incl;
    __syncthreads();
    int prefix = 0;
    for (int k = 0; k < w; ++k) prefix += wsum[k];
    if (threadIdx.x < nb) bsum[threadIdx.x] = prefix + incl - v;
}

__global__ void scan_add(int* __restrict__ offs, const int* __restrict__ bsum,
                         int N, int E) {
    const int i = blockIdx.x * 256 + threadIdx.x;
    if (i < N) offs[i] += bsum[blockIdx.x];
    if (i == 0) offs[N] = E;
}

__global__ void scatter_edges(const int* __restrict__ ei, int E_raw, int N,
                              int* __restrict__ curs, int* __restrict__ csr_src) {
    const int E = E_raw + N;
    for (int e = blockIdx.x * blockDim.x + threadIdx.x; e < E; e += gridDim.x * blockDim.x) {
        int s, d;
        if (e < E_raw) { s = ei[e]; d = ei[E_raw + e]; } else { s = d = e - E_raw; }
        int pos = atomicAdd(&curs[d], 1);
        csr_src[pos] = s;
    }
}

// ---------- fused GAT per-dst kernel (no atomics) ----------
// One wave per destination node: softmax max/denom lane-parallel over edges,
// then serial edge loop with all 64 lanes covering the channel dim.
template<int HEADS>
__global__ __launch_bounds__(256) void gat_csr(const int* __restrict__ offs,
                                               const int* __restrict__ csr_src,
                                               const float* __restrict__ AS,
                                               const float* __restrict__ AD,
                                               const float* __restrict__ H,
                                               const float* __restrict__ bias,
                                               float* __restrict__ Out,
                                               int N, int do_relu) {
    const int lane = threadIdx.x & 63;
    const int wid = (int)((blockIdx.x * blockDim.x + threadIdx.x) >> 6);
    const int nw = (int)((gridDim.x * blockDim.x) >> 6);
    for (int n = wid; n < N; n += nw) {
        const int s0 = offs[n], s1 = offs[n + 1];
        float adv[HEADS], mx[HEADS], dn[HEADS];
#pragma unroll
        for (int h = 0; h < HEADS; ++h) { adv[h] = AD[n * HEADS + h]; mx[h] = -1e30f; dn[h] = 0.f; }
        // pass 1: per-head max (edge-parallel across lanes)
        for (int i = s0 + lane; i < s1; i += 64) {
            int s = csr_src[i];
#pragma unroll
            for (int h = 0; h < HEADS; ++h) {
                float e = AS[s * HEADS + h] + adv[h];
                e = e > 0.f ? e : NEG_SLOPE * e;
                mx[h] = fmaxf(mx[h], e);
            }
        }
#pragma unroll
        for (int h = 0; h < HEADS; ++h)
            for (int o = 1; o < 64; o <<= 1) mx[h] = fmaxf(mx[h], __shfl_xor(mx[h], o, 64));
        // pass 2: per-head denom
        for (int i = s0 + lane; i < s1; i += 64) {
            int s = csr_src[i];
#pragma unroll
            for (int h = 0; h < HEADS; ++h) {
                float e = AS[s * HEADS + h] + adv[h];
                e = e > 0.f ? e : NEG_SLOPE * e;
                dn[h] += __expf(e - mx[h]);
            }
        }
        float inv[HEADS];
#pragma unroll
        for (int h = 0; h < HEADS; ++h) {
            for (int o = 1; o < 64; o <<= 1) dn[h] += __shfl_xor(dn[h], o, 64);
            inv[h] = 1.f / (dn[h] + EPSF);
        }
        // pass 3: aggregate (channel-parallel across lanes, serial over edges)
        if (HEADS == 2) {
            const int myh = lane >> 5;  // cols 2*lane,2*lane+1 belong to head lane/32
            const float myad = adv[myh], mymx = mx[myh], myinv = inv[myh];
            float ax = 0.f, ay = 0.f;
#pragma unroll 4
            for (int i = s0; i < s1; ++i) {
                int s = csr_src[i];
                float e = AS[s * 2 + myh] + myad;
                e = e > 0.f ? e : NEG_SLOPE * e;
                float a = __expf(e - mymx) * myinv;
                float2 hv = *(const float2*)&H[(size_t)s * 128 + 2 * lane];
                ax = fmaf(hv.x, a, ax);
                ay = fmaf(hv.y, a, ay);
            }
            float ox = ax + bias[2 * lane], oy = ay + bias[2 * lane + 1];
            if (do_relu) { ox = fmaxf(ox, 0.f); oy = fmaxf(oy, 0.f); }
            float2 o2 = make_float2(ox, oy);
            *(float2*)&Out[(size_t)n * 128 + 2 * lane] = o2;
        } else {
            float acc = 0.f;
#pragma unroll 4
            for (int i = s0; i < s1; ++i) {
                int s = csr_src[i];
                float e = AS[s] + adv[0];
                e = e > 0.f ? e : NEG_SLOPE * e;
                float a = __expf(e - mx[0]) * inv[0];
                acc = fmaf(H[(size_t)s * 64 + lane], a, acc);
            }
            float o = acc + bias[lane];
            if (do_relu) o = fmaxf(o, 0.f);
            Out[(size_t)n * 64 + lane] = o;
        }
    }
}

extern "C" void kernel_launch(void* const* d_in, const int* in_sizes, int n_in,
                              void* d_out, int out_size, void* d_ws, size_t ws_size,
                              hipStream_t stream) {
    const float* x   = (const float*)d_in[0];
    const int*   ei  = (const int*)d_in[1];
    const float* W0  = (const float*)d_in[2];
    const float* as0 = (const float*)d_in[3];
    const float* ad0 = (const float*)d_in[4];
    const float* b0  = (const float*)d_in[5];
    const float* W1  = (const float*)d_in[6];
    const float* as1 = (const float*)d_in[7];
    const float* ad1 = (const float*)d_in[8];
    const float* b1  = (const float*)d_in[9];
    const float* W2  = (const float*)d_in[10];
    const float* as2 = (const float*)d_in[11];
    const float* ad2 = (const float*)d_in[12];
    const float* b2  = (const float*)d_in[13];

    const int N = in_sizes[0] / 128;
    const int E_raw = in_sizes[1] / 2;
    const int E = E_raw + N;

    char* ws = (char*)d_ws;
    size_t off = 0;
    auto alloc = [&](size_t bytes) {
        void* p = ws + off;
        off = (off + bytes + 255) & ~(size_t)255;
        return p;
    };
    float* hbuf = (float*)alloc((size_t)N * 128 * 4);
    float* obuf = (float*)alloc((size_t)N * 128 * 4);
    float* asb  = (float*)alloc((size_t)N * 2 * 4);
    float* adb  = (float*)alloc((size_t)N * 2 * 4);
    int*   cnt  = (int*)alloc((size_t)N * 4);
    int*   offs = (int*)alloc((size_t)(N + 1) * 4);
    int*   curs = (int*)alloc((size_t)N * 4);
    int*   bsum = (int*)alloc(1024);
    int* csr_src = (int*)alloc((size_t)E * 4);
    (void)ws_size; (void)n_in; (void)out_size;

    // ---- build CSR grouped by dst (once; reused by all 3 layers) ----
    const int nb = (N + 255) / 256;
    hipMemsetAsync(cnt, 0, (size_t)N * 4, stream);
    hist_kernel<<<1024, 256, 0, stream>>>(ei, E_raw, N, cnt);
    scan_block<<<nb, 256, 0, stream>>>(cnt, offs, bsum, N);
    scan_bsum<<<1, 256, 0, stream>>>(bsum, nb);
    scan_add<<<nb, 256, 0, stream>>>(offs, bsum, N, E);
    hipMemcpyAsync(curs, offs, (size_t)N * 4, hipMemcpyDeviceToDevice, stream);
    scatter_edges<<<1024, 256, 0, stream>>>(ei, E_raw, N, curs, csr_src);

    const int gat_blocks = (N * 64 + 255) / 256;  // one wave per node

    auto run_layer = [&](const float* Xin, const float* W, const float* a_s,
                         const float* a_d, const float* b, int HEADS,
                         float* Hl, float* Oout, int do_relu) {
        const int gblocks = (N + 31) / 32;
        if (HEADS == 2) gemm128<128><<<gblocks, 256, 0, stream>>>(Xin, W, Hl, N);
        else            gemm128<64><<<gblocks, 256, 0, stream>>>(Xin, W, Hl, N);
        alphas_kernel<<<512, 256, 0, stream>>>(Hl, a_s, a_d, asb, adb, N, HEADS);
        if (HEADS == 2)
            gat_csr<2><<<gat_blocks, 256, 0, stream>>>(offs, csr_src, asb, adb, Hl, b, Oout, N, do_relu);
        else
            gat_csr<1><<<gat_blocks, 256, 0, stream>>>(offs, csr_src, asb, adb, Hl, b, Oout, N, do_relu);
    };

    // Layer 0: x -> obuf (relu)
    run_layer(x, W0, as0, ad0, b0, 2, hbuf, obuf, 1);
    // Layer 1: obuf -> obuf (gemm reads obuf into hbuf first; stream-ordered)
    run_layer(obuf, W1, as1, ad1, b1, 2, hbuf, obuf, 1);
    // Layer 2: obuf -> d_out (heads=1, no relu)
    run_layer(obuf, W2, as2, ad2, b2, 1, hbuf, (float*)d_out, 0);
}

// Round 3
// 395.594 us; speedup vs baseline: 4.0443x; 1.3226x over previous
//
#include <hip/hip_runtime.h>

#define NEG_SLOPE 0.2f
#define EPSF 1e-16f

// ---------- GEMM + fused alpha epilogue ----------
// h = X[N,128] @ W[128,BN]; also AS[n,h] = dot(h[n,h,:], asrc[h,:]), AD likewise.
// BM=64, BK=32, 256 threads, thread tile 4 x TN (TN = BN/16).
template<int BN, int HEADS>
__global__ __launch_bounds__(256) void gemm_fused(const float* __restrict__ X,
                                                  const float* __restrict__ W,
                                                  const float* __restrict__ asrc,
                                                  const float* __restrict__ adst,
                                                  float* __restrict__ Out,
                                                  float* __restrict__ AS,
                                                  float* __restrict__ AD, int N) {
    constexpr int BM = 64, BK = 32, K = 128;
    constexpr int TN = BN / 16;  // 8 (BN=128) or 4 (BN=64)
    __shared__ float Xs[BM][BK + 4];
    __shared__ float Ws[BK][BN];
    const int tid = threadIdx.x;
    const int tx = tid & 15, ty = tid >> 4;
    const int row0 = blockIdx.x * BM;

    float acc[4][TN];
#pragma unroll
    for (int i = 0; i < 4; ++i)
#pragma unroll
        for (int j = 0; j < TN; ++j) acc[i][j] = 0.f;

    for (int kb = 0; kb < K; kb += BK) {
        __syncthreads();
        // stage W tile [BK][BN], coalesced float4
        for (int idx = tid; idx < BK * (BN / 4); idx += 256) {
            int r = idx / (BN / 4), c4 = idx % (BN / 4);
            ((float4*)&Ws[r][0])[c4] = ((const float4*)&W[(size_t)(kb + r) * BN])[c4];
        }
        // stage X tile [BM][BK] (padded), coalesced float4 along k
        for (int t = tid; t < BM * (BK / 4); t += 256) {
            int r = t >> 3, c4 = t & 7;
            int gr = row0 + r;
            float4 v = make_float4(0.f, 0.f, 0.f, 0.f);
            if (gr < N) v = *((const float4*)&X[(size_t)gr * K + kb + c4 * 4]);
            Xs[r][c4 * 4 + 0] = v.x; Xs[r][c4 * 4 + 1] = v.y;
            Xs[r][c4 * 4 + 2] = v.z; Xs[r][c4 * 4 + 3] = v.w;
        }
        __syncthreads();
#pragma unroll
        for (int k = 0; k < BK; ++k) {
            float xr[4];
#pragma unroll
            for (int i = 0; i < 4; ++i) xr[i] = Xs[ty * 4 + i][k];
            float wv[TN];
#pragma unroll
            for (int j4 = 0; j4 < TN / 4; ++j4) {
                float4 w4 = ((float4*)&Ws[k][0])[tx * (TN / 4) + j4];
                wv[j4 * 4 + 0] = w4.x; wv[j4 * 4 + 1] = w4.y;
                wv[j4 * 4 + 2] = w4.z; wv[j4 * 4 + 3] = w4.w;
            }
#pragma unroll
            for (int i = 0; i < 4; ++i)
#pragma unroll
                for (int j = 0; j < TN; ++j) acc[i][j] = fmaf(xr[i], wv[j], acc[i][j]);
        }
    }

    // alpha vectors for this thread's column slice
    float av[TN], dv[TN];
#pragma unroll
    for (int j = 0; j < TN; ++j) { av[j] = asrc[tx * TN + j]; dv[j] = adst[tx * TN + j]; }

#pragma unroll
    for (int i = 0; i < 4; ++i) {
        int gr = row0 + ty * 4 + i;
        if (gr >= N) continue;  // uniform across each shfl group (same ty)
#pragma unroll
        for (int j4 = 0; j4 < TN / 4; ++j4) {
            float4 o4 = make_float4(acc[i][j4 * 4 + 0], acc[i][j4 * 4 + 1],
                                    acc[i][j4 * 4 + 2], acc[i][j4 * 4 + 3]);
            *((float4*)&Out[(size_t)gr * BN + tx * TN + j4 * 4]) = o4;
        }
        float ps = 0.f, pd = 0.f;
#pragma unroll
        for (int j = 0; j < TN; ++j) { ps = fmaf(acc[i][j], av[j], ps); pd = fmaf(acc[i][j], dv[j], pd); }
        if (HEADS == 2) {
            // head = tx>>3; reduce over 8 lanes (tx bits 0..2)
            for (int o = 1; o < 8; o <<= 1) { ps += __shfl_xor(ps, o, 64); pd += __shfl_xor(pd, o, 64); }
            if ((tx & 7) == 0) { AS[gr * 2 + (tx >> 3)] = ps; AD[gr * 2 + (tx >> 3)] = pd; }
        } else {
            for (int o = 1; o < 16; o <<= 1) { ps += __shfl_xor(ps, o, 64); pd += __shfl_xor(pd, o, 64); }
            if (tx == 0) { AS[gr] = ps; AD[gr] = pd; }
        }
    }
}

// ---------- CSR build: histogram, scan, scatter ----------
__global__ void hist_kernel(const int* __restrict__ ei, int E_raw, int N,
                            int* __restrict__ cnt) {
    const int E = E_raw + N;
    for (int e = blockIdx.x * blockDim.x + threadIdx.x; e < E; e += gridDim.x * blockDim.x) {
        int d = (e < E_raw) ? ei[E_raw + e] : e - E_raw;
        atomicAdd(&cnt[d], 1);
    }
}

__global__ __launch_bounds__(256) void scan_block(const int* __restrict__ cnt,
                                                  int* __restrict__ offs,
                                                  int* __restrict__ bsum, int N) {
    __shared__ int wsum[4];
    const int i = blockIdx.x * 256 + threadIdx.x;
    const int lane = threadIdx.x & 63, w = threadIdx.x >> 6;
    int v = (i < N) ? cnt[i] : 0;
    int incl = v;
    for (int o = 1; o < 64; o <<= 1) {
        int t = __shfl_up(incl, o, 64);
        if (lane >= o) incl += t;
    }
    if (lane == 63) wsum[w] = incl;
    __syncthreads();
    int prefix = 0;
    for (int k = 0; k < w; ++k) prefix += wsum[k];
    if (i < N) offs[i] = prefix + incl - v;
    if (threadIdx.x == 255) bsum[blockIdx.x] = prefix + incl;
}

__global__ __launch_bounds__(256) void scan_bsum(int* __restrict__ bsum, int nb) {
    __shared__ int wsum[4];
    const int lane = threadIdx.x & 63, w = threadIdx.x >> 6;
    int v = (threadIdx.x < nb) ? bsum[threadIdx.x] : 0;
    int incl = v;
    for (int o = 1; o < 64; o <<= 1) {
        int t = __shfl_up(incl, o, 64);
        if (lane >= o) incl += t;
    }
    if (lane == 63) wsum[w] = incl;
    __syncthreads();
    int prefix = 0;
    for (int k = 0; k < w; ++k) prefix += wsum[k];
    if (threadIdx.x < nb) bsum[threadIdx.x] = prefix + incl - v;
}

__global__ void scan_add(int* __restrict__ offs, const int* __restrict__ bsum,
                         int N, int E) {
    const int i = blockIdx.x * 256 + threadIdx.x;
    if (i < N) offs[i] += bsum[blockIdx.x];
    if (i == 0) offs[N] = E;
}

__global__ void scatter_edges(const int* __restrict__ ei, int E_raw, int N,
                              int* __restrict__ curs, int* __restrict__ csr_src) {
    const int E = E_raw + N;
    for (int e = blockIdx.x * blockDim.x + threadIdx.x; e < E; e += gridDim.x * blockDim.x) {
        int s, d;
        if (e < E_raw) { s = ei[e]; d = ei[E_raw + e]; } else { s = d = e - E_raw; }
        int pos = atomicAdd(&curs[d], 1);
        csr_src[pos] = s;
    }
}

// ---------- fused GAT per-dst kernel ----------
// One wave per destination node. No max-subtraction (logits are O(few units)):
// alpha_i = exp(e_i) / sum(exp(e_j)); 1/denom folded out of the edge loop.
// Fast path deg<=64: lane l caches (src, exp) of edge s0+l during the denom
// pass; aggregate pass replays them via __shfl (no re-gather, no re-exp).
template<int HEADS>
__global__ __launch_bounds__(256) void gat_csr(const int* __restrict__ offs,
                                               const int* __restrict__ csr_src,
                                               const float* __restrict__ AS,
                                               const float* __restrict__ AD,
                                               const float* __restrict__ H,
                                               const float* __restrict__ bias,
                                               float* __restrict__ Out,
                                               int N, int do_relu) {
    const int lane = threadIdx.x & 63;
    const int wid = (int)((blockIdx.x * blockDim.x + threadIdx.x) >> 6);
    const int nw = (int)((gridDim.x * blockDim.x) >> 6);
    for (int n = wid; n < N; n += nw) {
        const int s0 = offs[n], s1 = offs[n + 1];
        const int deg = s1 - s0;
        float adv0 = AD[n * HEADS];
        float adv1 = (HEADS == 2) ? AD[n * HEADS + 1] : 0.f;
        float dn0 = 0.f, dn1 = 0.f, p0 = 0.f, p1 = 0.f;
        int sreg = 0;
        for (int i = s0 + lane; i < s1; i += 64) {
            int s = csr_src[i];
            float pe0, pe1 = 0.f;
            if (HEADS == 2) {
                float2 a2 = *(const float2*)&AS[(size_t)s * 2];
                float e0 = a2.x + adv0, e1 = a2.y + adv1;
                e0 = e0 > 0.f ? e0 : NEG_SLOPE * e0;
                e1 = e1 > 0.f ? e1 : NEG_SLOPE * e1;
                pe0 = __expf(e0); pe1 = __expf(e1);
                dn0 += pe0; dn1 += pe1;
            } else {
                float e0 = AS[s] + adv0;
                e0 = e0 > 0.f ? e0 : NEG_SLOPE * e0;
                pe0 = __expf(e0);
                dn0 += pe0;
            }
            if (i == s0 + lane) { sreg = s; p0 = pe0; p1 = pe1; }
        }
        for (int o = 1; o < 64; o <<= 1) dn0 += __shfl_xor(dn0, o, 64);
        float inv0 = 1.f / (dn0 + EPSF), inv1 = 0.f;
        if (HEADS == 2) {
            for (int o = 1; o < 64; o <<= 1) dn1 += __shfl_xor(dn1, o, 64);
            inv1 = 1.f / (dn1 + EPSF);
        }

        if (HEADS == 2) {
            const int myh = lane >> 5;
            const float myinv = myh ? inv1 : inv0;
            float ax = 0.f, ay = 0.f;
            if (deg <= 64) {
#pragma unroll 4
                for (int i = 0; i < deg; ++i) {
                    int s = __shfl(sreg, i, 64);
                    float pa = __shfl(p0, i, 64);
                    float pb = __shfl(p1, i, 64);
                    float px = myh ? pb : pa;
                    float2 hv = *(const float2*)&H[(size_t)s * 128 + 2 * lane];
                    ax = fmaf(hv.x, px, ax);
                    ay = fmaf(hv.y, px, ay);
                }
            } else {
                const float myad = myh ? adv1 : adv0;
#pragma unroll 4
                for (int i = s0; i < s1; ++i) {
                    int s = csr_src[i];
                    float e = AS[(size_t)s * 2 + myh] + myad;
                    e = e > 0.f ? e : NEG_SLOPE * e;
                    float px = __expf(e);
                    float2 hv = *(const float2*)&H[(size_t)s * 128 + 2 * lane];
                    ax = fmaf(hv.x, px, ax);
                    ay = fmaf(hv.y, px, ay);
                }
            }
            float ox = fmaf(ax, myinv, 0.f) + bias[2 * lane];
            float oy = fmaf(ay, myinv, 0.f) + bias[2 * lane + 1];
            if (do_relu) { ox = fmaxf(ox, 0.f); oy = fmaxf(oy, 0.f); }
            *(float2*)&Out[(size_t)n * 128 + 2 * lane] = make_float2(ox, oy);
        } else {
            float acc = 0.f;
            if (deg <= 64) {
#pragma unroll 4
                for (int i = 0; i < deg; ++i) {
                    int s = __shfl(sreg, i, 64);
                    float px = __shfl(p0, i, 64);
                    acc = fmaf(H[(size_t)s * 64 + lane], px, acc);
                }
            } else {
#pragma unroll 4
                for (int i = s0; i < s1; ++i) {
                    int s = csr_src[i];
                    float e = AS[s] + adv0;
                    e = e > 0.f ? e : NEG_SLOPE * e;
                    acc = fmaf(H[(size_t)s * 64 + lane], __expf(e), acc);
                }
            }
            float o = acc * inv0 + bias[lane];
            if (do_relu) o = fmaxf(o, 0.f);
            Out[(size_t)n * 64 + lane] = o;
        }
    }
}

extern "C" void kernel_launch(void* const* d_in, const int* in_sizes, int n_in,
                              void* d_out, int out_size, void* d_ws, size_t ws_size,
                              hipStream_t stream) {
    const float* x   = (const float*)d_in[0];
    const int*   ei  = (const int*)d_in[1];
    const float* W0  = (const float*)d_in[2];
    const float* as0 = (const float*)d_in[3];
    const float* ad0 = (const float*)d_in[4];
    const float* b0  = (const float*)d_in[5];
    const float* W1  = (const float*)d_in[6];
    const float* as1 = (const float*)d_in[7];
    const float* ad1 = (const float*)d_in[8];
    const float* b1  = (const float*)d_in[9];
    const float* W2  = (const float*)d_in[10];
    const float* as2 = (const float*)d_in[11];
    const float* ad2 = (const float*)d_in[12];
    const float* b2  = (const float*)d_in[13];

    const int N = in_sizes[0] / 128;
    const int E_raw = in_sizes[1] / 2;
    const int E = E_raw + N;

    char* ws = (char*)d_ws;
    size_t off = 0;
    auto alloc = [&](size_t bytes) {
        void* p = ws + off;
        off = (off + bytes + 255) & ~(size_t)255;
        return p;
    };
    float* hbuf = (float*)alloc((size_t)N * 128 * 4);
    float* obuf = (float*)alloc((size_t)N * 128 * 4);
    float* asb  = (float*)alloc((size_t)N * 2 * 4);
    float* adb  = (float*)alloc((size_t)N * 2 * 4);
    int*   cnt  = (int*)alloc((size_t)N * 4);
    int*   offs = (int*)alloc((size_t)(N + 1) * 4);
    int*   curs = (int*)alloc((size_t)N * 4);
    int*   bsum = (int*)alloc(1024);
    int* csr_src = (int*)alloc((size_t)E * 4);
    (void)ws_size; (void)n_in; (void)out_size;

    // ---- build CSR grouped by dst (once; reused by all 3 layers) ----
    const int nb = (N + 255) / 256;
    hipMemsetAsync(cnt, 0, (size_t)N * 4, stream);
    hist_kernel<<<1024, 256, 0, stream>>>(ei, E_raw, N, cnt);
    scan_block<<<nb, 256, 0, stream>>>(cnt, offs, bsum, N);
    scan_bsum<<<1, 256, 0, stream>>>(bsum, nb);
    scan_add<<<nb, 256, 0, stream>>>(offs, bsum, N, E);
    hipMemcpyAsync(curs, offs, (size_t)N * 4, hipMemcpyDeviceToDevice, stream);
    scatter_edges<<<1024, 256, 0, stream>>>(ei, E_raw, N, curs, csr_src);

    const int gemm_blocks = (N + 63) / 64;
    const int gat_blocks = (N * 64 + 255) / 256;

    // Layer 0
    gemm_fused<128, 2><<<gemm_blocks, 256, 0, stream>>>(x, W0, as0, ad0, hbuf, asb, adb, N);
    gat_csr<2><<<gat_blocks, 256, 0, stream>>>(offs, csr_src, asb, adb, hbuf, b0, obuf, N, 1);
    // Layer 1
    gemm_fused<128, 2><<<gemm_blocks, 256, 0, stream>>>(obuf, W1, as1, ad1, hbuf, asb, adb, N);
    gat_csr<2><<<gat_blocks, 256, 0, stream>>>(offs, csr_src, asb, adb, hbuf, b1, obuf, N, 1);
    // Layer 2
    gemm_fused<64, 1><<<gemm_blocks, 256, 0, stream>>>(obuf, W2, as2, ad2, hbuf, asb, adb, N);
    gat_csr<1><<<gat_blocks, 256, 0, stream>>>(offs, csr_src, asb, adb, hbuf, b2, (float*)d_out, N, 0);
}

// Round 4
// 351.222 us; speedup vs baseline: 4.5553x; 1.1263x over previous
//
#include <hip/hip_runtime.h>
#include <hip/hip_fp16.h>

#define NEG_SLOPE 0.2f
#define EPSF 1e-16f

// ---------- GEMM + fused alpha epilogue ----------
// h = X[N,128] @ W[128,BN]; AS[n,h] = dot(h[n,h,:], asrc[h,:]), AD likewise.
// BM=64, BK=32, 256 threads, thread tile 4 x TN (TN = BN/16).
// OUTH: write h as __half (for heads=2 gather layers) else float.
template<int BN, int HEADS, bool OUTH>
__global__ __launch_bounds__(256) void gemm_fused(const float* __restrict__ X,
                                                  const float* __restrict__ W,
                                                  const float* __restrict__ asrc,
                                                  const float* __restrict__ adst,
                                                  float* __restrict__ OutF,
                                                  __half* __restrict__ OutH,
                                                  float* __restrict__ AS,
                                                  float* __restrict__ AD, int N) {
    constexpr int BM = 64, BK = 32, K = 128;
    constexpr int TN = BN / 16;  // 8 (BN=128) or 4 (BN=64)
    __shared__ float Xs[BM][BK + 4];
    __shared__ float Ws[BK][BN];
    const int tid = threadIdx.x;
    const int tx = tid & 15, ty = tid >> 4;
    const int row0 = blockIdx.x * BM;

    float acc[4][TN];
#pragma unroll
    for (int i = 0; i < 4; ++i)
#pragma unroll
        for (int j = 0; j < TN; ++j) acc[i][j] = 0.f;

    for (int kb = 0; kb < K; kb += BK) {
        __syncthreads();
        for (int idx = tid; idx < BK * (BN / 4); idx += 256) {
            int r = idx / (BN / 4), c4 = idx % (BN / 4);
            ((float4*)&Ws[r][0])[c4] = ((const float4*)&W[(size_t)(kb + r) * BN])[c4];
        }
        for (int t = tid; t < BM * (BK / 4); t += 256) {
            int r = t >> 3, c4 = t & 7;
            int gr = row0 + r;
            float4 v = make_float4(0.f, 0.f, 0.f, 0.f);
            if (gr < N) v = *((const float4*)&X[(size_t)gr * K + kb + c4 * 4]);
            Xs[r][c4 * 4 + 0] = v.x; Xs[r][c4 * 4 + 1] = v.y;
            Xs[r][c4 * 4 + 2] = v.z; Xs[r][c4 * 4 + 3] = v.w;
        }
        __syncthreads();
#pragma unroll
        for (int k = 0; k < BK; ++k) {
            float xr[4];
#pragma unroll
            for (int i = 0; i < 4; ++i) xr[i] = Xs[ty * 4 + i][k];
            float wv[TN];
#pragma unroll
            for (int j4 = 0; j4 < TN / 4; ++j4) {
                float4 w4 = ((float4*)&Ws[k][0])[tx * (TN / 4) + j4];
                wv[j4 * 4 + 0] = w4.x; wv[j4 * 4 + 1] = w4.y;
                wv[j4 * 4 + 2] = w4.z; wv[j4 * 4 + 3] = w4.w;
            }
#pragma unroll
            for (int i = 0; i < 4; ++i)
#pragma unroll
                for (int j = 0; j < TN; ++j) acc[i][j] = fmaf(xr[i], wv[j], acc[i][j]);
        }
    }

    float av[TN], dv[TN];
#pragma unroll
    for (int j = 0; j < TN; ++j) { av[j] = asrc[tx * TN + j]; dv[j] = adst[tx * TN + j]; }

#pragma unroll
    for (int i = 0; i < 4; ++i) {
        int gr = row0 + ty * 4 + i;
        if (gr >= N) continue;  // uniform across each shfl group (same ty)
        if (OUTH) {
            __half2 hp[TN / 2];
#pragma unroll
            for (int j2 = 0; j2 < TN / 2; ++j2)
                hp[j2] = __floats2half2_rn(acc[i][j2 * 2], acc[i][j2 * 2 + 1]);
            if (TN == 8)
                *((uint4*)&OutH[(size_t)gr * BN + tx * TN]) = *(uint4*)hp;
            else
                *((uint2*)&OutH[(size_t)gr * BN + tx * TN]) = *(uint2*)hp;
        } else {
#pragma unroll
            for (int j4 = 0; j4 < TN / 4; ++j4) {
                float4 o4 = make_float4(acc[i][j4 * 4 + 0], acc[i][j4 * 4 + 1],
                                        acc[i][j4 * 4 + 2], acc[i][j4 * 4 + 3]);
                *((float4*)&OutF[(size_t)gr * BN + tx * TN + j4 * 4]) = o4;
            }
        }
        float ps = 0.f, pd = 0.f;
#pragma unroll
        for (int j = 0; j < TN; ++j) { ps = fmaf(acc[i][j], av[j], ps); pd = fmaf(acc[i][j], dv[j], pd); }
        if (HEADS == 2) {
            for (int o = 1; o < 8; o <<= 1) { ps += __shfl_xor(ps, o, 64); pd += __shfl_xor(pd, o, 64); }
            if ((tx & 7) == 0) { AS[gr * 2 + (tx >> 3)] = ps; AD[gr * 2 + (tx >> 3)] = pd; }
        } else {
            for (int o = 1; o < 16; o <<= 1) { ps += __shfl_xor(ps, o, 64); pd += __shfl_xor(pd, o, 64); }
            if (tx == 0) { AS[gr] = ps; AD[gr] = pd; }
        }
    }
}

// ---------- CSR build ----------
__global__ void hist_kernel(const int* __restrict__ ei, int E_raw, int N,
                            int* __restrict__ cnt) {
    const int E = E_raw + N;
    for (int e = blockIdx.x * blockDim.x + threadIdx.x; e < E; e += gridDim.x * blockDim.x) {
        int d = (e < E_raw) ? ei[E_raw + e] : e - E_raw;
        atomicAdd(&cnt[d], 1);
    }
}

__global__ __launch_bounds__(256) void scan_block(const int* __restrict__ cnt,
                                                  int* __restrict__ offs,
                                                  int* __restrict__ bsum, int N) {
    __shared__ int wsum[4];
    const int i = blockIdx.x * 256 + threadIdx.x;
    const int lane = threadIdx.x & 63, w = threadIdx.x >> 6;
    int v = (i < N) ? cnt[i] : 0;
    int incl = v;
    for (int o = 1; o < 64; o <<= 1) {
        int t = __shfl_up(incl, o, 64);
        if (lane >= o) incl += t;
    }
    if (lane == 63) wsum[w] = incl;
    __syncthreads();
    int prefix = 0;
    for (int k = 0; k < w; ++k) prefix += wsum[k];
    if (i < N) offs[i] = prefix + incl - v;
    if (threadIdx.x == 255) bsum[blockIdx.x] = prefix + incl;
}

__global__ __launch_bounds__(256) void scan_bsum(int* __restrict__ bsum, int nb) {
    __shared__ int wsum[4];
    const int lane = threadIdx.x & 63, w = threadIdx.x >> 6;
    int v = (threadIdx.x < nb) ? bsum[threadIdx.x] : 0;
    int incl = v;
    for (int o = 1; o < 64; o <<= 1) {
        int t = __shfl_up(incl, o, 64);
        if (lane >= o) incl += t;
    }
    if (lane == 63) wsum[w] = incl;
    __syncthreads();
    int prefix = 0;
    for (int k = 0; k < w; ++k) prefix += wsum[k];
    if (threadIdx.x < nb) bsum[threadIdx.x] = prefix + incl - v;
}

__global__ void scan_add(int* __restrict__ offs, const int* __restrict__ bsum,
                         int N, int E) {
    const int i = blockIdx.x * 256 + threadIdx.x;
    if (i < N) offs[i] += bsum[blockIdx.x];
    if (i == 0) offs[N] = E;
}

__global__ void scatter_edges(const int* __restrict__ ei, int E_raw, int N,
                              int* __restrict__ curs, int* __restrict__ csr_src) {
    const int E = E_raw + N;
    for (int e = blockIdx.x * blockDim.x + threadIdx.x; e < E; e += gridDim.x * blockDim.x) {
        int s, d;
        if (e < E_raw) { s = ei[e]; d = ei[E_raw + e]; } else { s = d = e - E_raw; }
        int pos = atomicAdd(&curs[d], 1);
        csr_src[pos] = s;
    }
}

// ---------- fused GAT per-dst, heads=2, fp16 H ----------
// One wave per dst node. alpha_i = exp(e_i)/sum exp(e_j) (no max-sub; logits O(1)).
// deg<=64 fast path: lane l caches (src, exp0, exp1) of edge s0+l; aggregate
// replays via shfl with an explicit 8-deep load/FMA pipeline.
__global__ __launch_bounds__(256) void gat_csr2(const int* __restrict__ offs,
                                                const int* __restrict__ csr_src,
                                                const float* __restrict__ AS,
                                                const float* __restrict__ AD,
                                                const __half* __restrict__ H,
                                                const float* __restrict__ bias,
                                                float* __restrict__ Out,
                                                int N, int do_relu) {
    const int lane = threadIdx.x & 63;
    const int wid = (int)((blockIdx.x * blockDim.x + threadIdx.x) >> 6);
    const int nw = (int)((gridDim.x * blockDim.x) >> 6);
    const __half2* __restrict__ H2 = (const __half2*)H;
    for (int n = wid; n < N; n += nw) {
        const int s0 = offs[n], s1 = offs[n + 1];
        const int deg = s1 - s0;
        const float2 adv = *(const float2*)&AD[(size_t)n * 2];
        float dn0 = 0.f, dn1 = 0.f, p0 = 0.f, p1 = 0.f;
        int sreg = 0;
        for (int i = s0 + lane; i < s1; i += 64) {
            int s = csr_src[i];
            float2 a2 = *(const float2*)&AS[(size_t)s * 2];
            float e0 = a2.x + adv.x, e1 = a2.y + adv.y;
            e0 = e0 > 0.f ? e0 : NEG_SLOPE * e0;
            e1 = e1 > 0.f ? e1 : NEG_SLOPE * e1;
            float pe0 = __expf(e0), pe1 = __expf(e1);
            dn0 += pe0; dn1 += pe1;
            if (i == s0 + lane) { sreg = s; p0 = pe0; p1 = pe1; }
        }
        for (int o = 1; o < 64; o <<= 1) {
            dn0 += __shfl_xor(dn0, o, 64);
            dn1 += __shfl_xor(dn1, o, 64);
        }
        const int myh = lane >> 5;
        const float myinv = 1.f / ((myh ? dn1 : dn0) + EPSF);
        float ax = 0.f, ay = 0.f;
        if (deg <= 64) {
            for (int base = 0; base < deg; base += 8) {
                const int cnt = min(8, deg - base);
                __half2 hv[8];
                float pw[8];
#pragma unroll 8
                for (int j = 0; j < 8; ++j) {
                    if (j < cnt) {
                        int s = __shfl(sreg, base + j, 64);
                        float pa = __shfl(p0, base + j, 64);
                        float pb = __shfl(p1, base + j, 64);
                        pw[j] = myh ? pb : pa;
                        hv[j] = H2[(size_t)s * 64 + lane];
                    }
                }
#pragma unroll 8
                for (int j = 0; j < 8; ++j) {
                    if (j < cnt) {
                        float2 f = __half22float2(hv[j]);
                        ax = fmaf(f.x, pw[j], ax);
                        ay = fmaf(f.y, pw[j], ay);
                    }
                }
            }
        } else {
            const float myad = myh ? adv.y : adv.x;
            for (int i = s0; i < s1; ++i) {
                int s = csr_src[i];
                float e = AS[(size_t)s * 2 + myh] + myad;
                e = e > 0.f ? e : NEG_SLOPE * e;
                float px = __expf(e);
                float2 f = __half22float2(H2[(size_t)s * 64 + lane]);
                ax = fmaf(f.x, px, ax);
                ay = fmaf(f.y, px, ay);
            }
        }
        float ox = ax * myinv + bias[2 * lane];
        float oy = ay * myinv + bias[2 * lane + 1];
        if (do_relu) { ox = fmaxf(ox, 0.f); oy = fmaxf(oy, 0.f); }
        *(float2*)&Out[(size_t)n * 128 + 2 * lane] = make_float2(ox, oy);
    }
}

// ---------- fused GAT per-dst, heads=1, fp32 H (final layer) ----------
__global__ __launch_bounds__(256) void gat_csr1(const int* __restrict__ offs,
                                                const int* __restrict__ csr_src,
                                                const float* __restrict__ AS,
                                                const float* __restrict__ AD,
                                                const float* __restrict__ H,
                                                const float* __restrict__ bias,
                                                float* __restrict__ Out,
                                                int N, int do_relu) {
    const int lane = threadIdx.x & 63;
    const int wid = (int)((blockIdx.x * blockDim.x + threadIdx.x) >> 6);
    const int nw = (int)((gridDim.x * blockDim.x) >> 6);
    for (int n = wid; n < N; n += nw) {
        const int s0 = offs[n], s1 = offs[n + 1];
        const int deg = s1 - s0;
        const float adv0 = AD[n];
        float dn0 = 0.f, p0 = 0.f;
        int sreg = 0;
        for (int i = s0 + lane; i < s1; i += 64) {
            int s = csr_src[i];
            float e0 = AS[s] + adv0;
            e0 = e0 > 0.f ? e0 : NEG_SLOPE * e0;
            float pe0 = __expf(e0);
            dn0 += pe0;
            if (i == s0 + lane) { sreg = s; p0 = pe0; }
        }
        for (int o = 1; o < 64; o <<= 1) dn0 += __shfl_xor(dn0, o, 64);
        const float inv0 = 1.f / (dn0 + EPSF);
        float acc = 0.f;
        if (deg <= 64) {
            for (int base = 0; base < deg; base += 8) {
                const int cnt = min(8, deg - base);
                float hv[8], pw[8];
#pragma unroll 8
                for (int j = 0; j < 8; ++j) {
                    if (j < cnt) {
                        int s = __shfl(sreg, base + j, 64);
                        pw[j] = __shfl(p0, base + j, 64);
                        hv[j] = H[(size_t)s * 64 + lane];
                    }
                }
#pragma unroll 8
                for (int j = 0; j < 8; ++j)
                    if (j < cnt) acc = fmaf(hv[j], pw[j], acc);
            }
        } else {
            for (int i = s0; i < s1; ++i) {
                int s = csr_src[i];
                float e = AS[s] + adv0;
                e = e > 0.f ? e : NEG_SLOPE * e;
                acc = fmaf(H[(size_t)s * 64 + lane], __expf(e), acc);
            }
        }
        float o = acc * inv0 + bias[lane];
        if (do_relu) o = fmaxf(o, 0.f);
        Out[(size_t)n * 64 + lane] = o;
    }
}

extern "C" void kernel_launch(void* const* d_in, const int* in_sizes, int n_in,
                              void* d_out, int out_size, void* d_ws, size_t ws_size,
                              hipStream_t stream) {
    const float* x   = (const float*)d_in[0];
    const int*   ei  = (const int*)d_in[1];
    const float* W0  = (const float*)d_in[2];
    const float* as0 = (const float*)d_in[3];
    const float* ad0 = (const float*)d_in[4];
    const float* b0  = (const float*)d_in[5];
    const float* W1  = (const float*)d_in[6];
    const float* as1 = (const float*)d_in[7];
    const float* ad1 = (const float*)d_in[8];
    const float* b1  = (const float*)d_in[9];
    const float* W2  = (const float*)d_in[10];
    const float* as2 = (const float*)d_in[11];
    const float* ad2 = (const float*)d_in[12];
    const float* b2  = (const float*)d_in[13];

    const int N = in_sizes[0] / 128;
    const int E_raw = in_sizes[1] / 2;
    const int E = E_raw + N;

    char* ws = (char*)d_ws;
    size_t off = 0;
    auto alloc = [&](size_t bytes) {
        void* p = ws + off;
        off = (off + bytes + 255) & ~(size_t)255;
        return p;
    };
    float* hbuf = (float*)alloc((size_t)N * 128 * 4);  // fp32 h (layer2) / fp16 h alias
    float* obuf = (float*)alloc((size_t)N * 128 * 4);
    float* asb  = (float*)alloc((size_t)N * 2 * 4);
    float* adb  = (float*)alloc((size_t)N * 2 * 4);
    int*   cnt  = (int*)alloc((size_t)N * 4);
    int*   offs = (int*)alloc((size_t)(N + 1) * 4);
    int*   curs = (int*)alloc((size_t)N * 4);
    int*   bsum = (int*)alloc(1024);
    int* csr_src = (int*)alloc((size_t)E * 4);
    __half* hh = (__half*)hbuf;
    (void)ws_size; (void)n_in; (void)out_size;

    // ---- build CSR grouped by dst (reused by all 3 layers) ----
    const int nb = (N + 255) / 256;
    hipMemsetAsync(cnt, 0, (size_t)N * 4, stream);
    hist_kernel<<<1024, 256, 0, stream>>>(ei, E_raw, N, cnt);
    scan_block<<<nb, 256, 0, stream>>>(cnt, offs, bsum, N);
    scan_bsum<<<1, 256, 0, stream>>>(bsum, nb);
    scan_add<<<nb, 256, 0, stream>>>(offs, bsum, N, E);
    hipMemcpyAsync(curs, offs, (size_t)N * 4, hipMemcpyDeviceToDevice, stream);
    scatter_edges<<<1024, 256, 0, stream>>>(ei, E_raw, N, curs, csr_src);

    const int gemm_blocks = (N + 63) / 64;
    const int gat_blocks = (N * 64 + 255) / 256;

    // Layer 0: x -> obuf (relu)
    gemm_fused<128, 2, true><<<gemm_blocks, 256, 0, stream>>>(x, W0, as0, ad0, nullptr, hh, asb, adb, N);
    gat_csr2<<<gat_blocks, 256, 0, stream>>>(offs, csr_src, asb, adb, hh, b0, obuf, N, 1);
    // Layer 1: obuf -> obuf
    gemm_fused<128, 2, true><<<gemm_blocks, 256, 0, stream>>>(obuf, W1, as1, ad1, nullptr, hh, asb, adb, N);
    gat_csr2<<<gat_blocks, 256, 0, stream>>>(offs, csr_src, asb, adb, hh, b1, obuf, N, 1);
    // Layer 2: obuf -> d_out (heads=1, fp32 path, no relu)
    gemm_fused<64, 1, false><<<gemm_blocks, 256, 0, stream>>>(obuf, W2, as2, ad2, hbuf, nullptr, asb, adb, N);
    gat_csr1<<<gat_blocks, 256, 0, stream>>>(offs, csr_src, asb, adb, hbuf, b2, (float*)d_out, N, 0);
}

// Round 5
// 313.565 us; speedup vs baseline: 5.1023x; 1.1201x over previous
//
#include <hip/hip_runtime.h>
#include <hip/hip_fp16.h>

#define NEG_SLOPE 0.2f
#define EPSF 1e-16f

// ---------- GEMM + fused alpha epilogue ----------
template<int BN, int HEADS, bool OUTH>
__global__ __launch_bounds__(256) void gemm_fused(const float* __restrict__ X,
                                                  const float* __restrict__ W,
                                                  const float* __restrict__ asrc,
                                                  const float* __restrict__ adst,
                                                  float* __restrict__ OutF,
                                                  __half* __restrict__ OutH,
                                                  float* __restrict__ AS,
                                                  float* __restrict__ AD, int N) {
    constexpr int BM = 64, BK = 32, K = 128;
    constexpr int TN = BN / 16;  // 8 (BN=128) or 4 (BN=64)
    __shared__ float Xs[BM][BK + 4];
    __shared__ float Ws[BK][BN];
    const int tid = threadIdx.x;
    const int tx = tid & 15, ty = tid >> 4;
    const int row0 = blockIdx.x * BM;

    float acc[4][TN];
#pragma unroll
    for (int i = 0; i < 4; ++i)
#pragma unroll
        for (int j = 0; j < TN; ++j) acc[i][j] = 0.f;

    for (int kb = 0; kb < K; kb += BK) {
        __syncthreads();
        for (int idx = tid; idx < BK * (BN / 4); idx += 256) {
            int r = idx / (BN / 4), c4 = idx % (BN / 4);
            ((float4*)&Ws[r][0])[c4] = ((const float4*)&W[(size_t)(kb + r) * BN])[c4];
        }
        for (int t = tid; t < BM * (BK / 4); t += 256) {
            int r = t >> 3, c4 = t & 7;
            int gr = row0 + r;
            float4 v = make_float4(0.f, 0.f, 0.f, 0.f);
            if (gr < N) v = *((const float4*)&X[(size_t)gr * K + kb + c4 * 4]);
            Xs[r][c4 * 4 + 0] = v.x; Xs[r][c4 * 4 + 1] = v.y;
            Xs[r][c4 * 4 + 2] = v.z; Xs[r][c4 * 4 + 3] = v.w;
        }
        __syncthreads();
#pragma unroll
        for (int k = 0; k < BK; ++k) {
            float xr[4];
#pragma unroll
            for (int i = 0; i < 4; ++i) xr[i] = Xs[ty * 4 + i][k];
            float wv[TN];
#pragma unroll
            for (int j4 = 0; j4 < TN / 4; ++j4) {
                float4 w4 = ((float4*)&Ws[k][0])[tx * (TN / 4) + j4];
                wv[j4 * 4 + 0] = w4.x; wv[j4 * 4 + 1] = w4.y;
                wv[j4 * 4 + 2] = w4.z; wv[j4 * 4 + 3] = w4.w;
            }
#pragma unroll
            for (int i = 0; i < 4; ++i)
#pragma unroll
                for (int j = 0; j < TN; ++j) acc[i][j] = fmaf(xr[i], wv[j], acc[i][j]);
        }
    }

    float av[TN], dv[TN];
#pragma unroll
    for (int j = 0; j < TN; ++j) { av[j] = asrc[tx * TN + j]; dv[j] = adst[tx * TN + j]; }

#pragma unroll
    for (int i = 0; i < 4; ++i) {
        int gr = row0 + ty * 4 + i;
        if (gr >= N) continue;
        if (OUTH) {
            __half2 hp[TN / 2];
#pragma unroll
            for (int j2 = 0; j2 < TN / 2; ++j2)
                hp[j2] = __floats2half2_rn(acc[i][j2 * 2], acc[i][j2 * 2 + 1]);
            if (TN == 8)
                *((uint4*)&OutH[(size_t)gr * BN + tx * TN]) = *(uint4*)hp;
            else
                *((uint2*)&OutH[(size_t)gr * BN + tx * TN]) = *(uint2*)hp;
        } else {
#pragma unroll
            for (int j4 = 0; j4 < TN / 4; ++j4) {
                float4 o4 = make_float4(acc[i][j4 * 4 + 0], acc[i][j4 * 4 + 1],
                                        acc[i][j4 * 4 + 2], acc[i][j4 * 4 + 3]);
                *((float4*)&OutF[(size_t)gr * BN + tx * TN + j4 * 4]) = o4;
            }
        }
        float ps = 0.f, pd = 0.f;
#pragma unroll
        for (int j = 0; j < TN; ++j) { ps = fmaf(acc[i][j], av[j], ps); pd = fmaf(acc[i][j], dv[j], pd); }
        if (HEADS == 2) {
            for (int o = 1; o < 8; o <<= 1) { ps += __shfl_xor(ps, o, 64); pd += __shfl_xor(pd, o, 64); }
            if ((tx & 7) == 0) { AS[gr * 2 + (tx >> 3)] = ps; AD[gr * 2 + (tx >> 3)] = pd; }
        } else {
            for (int o = 1; o < 16; o <<= 1) { ps += __shfl_xor(ps, o, 64); pd += __shfl_xor(pd, o, 64); }
            if (tx == 0) { AS[gr] = ps; AD[gr] = pd; }
        }
    }
}

// ---------- CSR build ----------
__global__ void hist_kernel(const int* __restrict__ ei, int E_raw, int N,
                            int* __restrict__ cnt) {
    const int E = E_raw + N;
    for (int e = blockIdx.x * blockDim.x + threadIdx.x; e < E; e += gridDim.x * blockDim.x) {
        int d = (e < E_raw) ? ei[E_raw + e] : e - E_raw;
        atomicAdd(&cnt[d], 1);
    }
}

__global__ __launch_bounds__(256) void scan_block(const int* __restrict__ cnt,
                                                  int* __restrict__ offs,
                                                  int* __restrict__ bsum, int N) {
    __shared__ int wsum[4];
    const int i = blockIdx.x * 256 + threadIdx.x;
    const int lane = threadIdx.x & 63, w = threadIdx.x >> 6;
    int v = (i < N) ? cnt[i] : 0;
    int incl = v;
    for (int o = 1; o < 64; o <<= 1) {
        int t = __shfl_up(incl, o, 64);
        if (lane >= o) incl += t;
    }
    if (lane == 63) wsum[w] = incl;
    __syncthreads();
    int prefix = 0;
    for (int k = 0; k < w; ++k) prefix += wsum[k];
    if (i < N) offs[i] = prefix + incl - v;
    if (threadIdx.x == 255) bsum[blockIdx.x] = prefix + incl;
}

__global__ __launch_bounds__(256) void scan_bsum(int* __restrict__ bsum, int nb) {
    __shared__ int wsum[4];
    const int lane = threadIdx.x & 63, w = threadIdx.x >> 6;
    int v = (threadIdx.x < nb) ? bsum[threadIdx.x] : 0;
    int incl = v;
    for (int o = 1; o < 64; o <<= 1) {
        int t = __shfl_up(incl, o, 64);
        if (lane >= o) incl += t;
    }
    if (lane == 63) wsum[w] = incl;
    __syncthreads();
    int prefix = 0;
    for (int k = 0; k < w; ++k) prefix += wsum[k];
    if (threadIdx.x < nb) bsum[threadIdx.x] = prefix + incl - v;
}

__global__ void scan_add(int* __restrict__ offs, const int* __restrict__ bsum,
                         int N, int E) {
    const int i = blockIdx.x * 256 + threadIdx.x;
    if (i < N) offs[i] += bsum[blockIdx.x];
    if (i == 0) offs[N] = E;
}

__global__ void scatter_edges(const int* __restrict__ ei, int E_raw, int N,
                              int* __restrict__ curs, int* __restrict__ csr_src) {
    const int E = E_raw + N;
    for (int e = blockIdx.x * blockDim.x + threadIdx.x; e < E; e += gridDim.x * blockDim.x) {
        int s, d;
        if (e < E_raw) { s = ei[e]; d = ei[E_raw + e]; } else { s = d = e - E_raw; }
        int pos = atomicAdd(&curs[d], 1);
        csr_src[pos] = s;
    }
}

// ---------- fused GAT per-dst, heads=2, fp16 H ----------
// Wave per dst node. Denom pass caches (src,p0,p1) per lane, dumps to LDS;
// aggregate: lanes split 32+32 over 2 edges/iter, each lane = 4 channels
// (uint2 gather), 8-pair batches with arrays to keep 8 gathers in flight.
__global__ __launch_bounds__(256) void gat_csr2(const int* __restrict__ offs,
                                                const int* __restrict__ csr_src,
                                                const float* __restrict__ AS,
                                                const float* __restrict__ AD,
                                                const __half* __restrict__ H,
                                                const float* __restrict__ bias,
                                                float* __restrict__ Out,
                                                int N, int do_relu) {
    __shared__ int   sS[4][64];
    __shared__ float sP0[4][64];
    __shared__ float sP1[4][64];
    const int lane = threadIdx.x & 63;
    const int w = threadIdx.x >> 6;
    const int wid = (int)((blockIdx.x * blockDim.x + threadIdx.x) >> 6);
    const int nw = (int)((gridDim.x * blockDim.x) >> 6);
    const int c = lane & 31;      // channel group: channels 4c..4c+3
    const int slot = lane >> 5;   // which of the 2 in-flight edges
    const int myh = c >> 4;       // head owning my channels
    int* const sSw = &sS[w][0];
    const float* const myp = myh ? &sP1[w][0] : &sP0[w][0];
    const float4 b4 = *(const float4*)&bias[4 * c];

    for (int n = wid; n < N; n += nw) {
        const int s0 = offs[n], s1 = offs[n + 1];
        const int deg = s1 - s0;
        const float2 adv = *(const float2*)&AD[(size_t)n * 2];
        float dn0 = 0.f, dn1 = 0.f, p0 = 0.f, p1 = 0.f;
        int sreg = 0;
        for (int i = s0 + lane; i < s1; i += 64) {
            int s = csr_src[i];
            float2 a2 = *(const float2*)&AS[(size_t)s * 2];
            float e0 = a2.x + adv.x, e1 = a2.y + adv.y;
            e0 = e0 > 0.f ? e0 : NEG_SLOPE * e0;
            e1 = e1 > 0.f ? e1 : NEG_SLOPE * e1;
            float pe0 = __expf(e0), pe1 = __expf(e1);
            dn0 += pe0; dn1 += pe1;
            if (i == s0 + lane) { sreg = s; p0 = pe0; p1 = pe1; }
        }
        for (int o = 1; o < 64; o <<= 1) {
            dn0 += __shfl_xor(dn0, o, 64);
            dn1 += __shfl_xor(dn1, o, 64);
        }
        const float myinv = 1.f / ((myh ? dn1 : dn0) + EPSF);

        float a0 = 0.f, a1 = 0.f, a2c = 0.f, a3 = 0.f;
        if (deg <= 64) {
            sSw[lane] = sreg;        // 0 for lanes >= deg
            sP0[w][lane] = p0;       // 0 for lanes >= deg
            sP1[w][lane] = p1;
            const int npc = (deg + 1) >> 1;  // pairs (phantom edge has p=0)
            int t = 0;
            for (; t + 8 <= npc; t += 8) {
                int ss[8]; float pw[8]; uint2 hv[8];
#pragma unroll
                for (int k = 0; k < 8; ++k) {
                    int idx = 2 * (t + k) + slot;
                    ss[k] = sSw[idx];
                    pw[k] = myp[idx];
                }
#pragma unroll
                for (int k = 0; k < 8; ++k)
                    hv[k] = *(const uint2*)&H[(size_t)ss[k] * 128 + 4 * c];
#pragma unroll
                for (int k = 0; k < 8; ++k) {
                    float2 f01 = __half22float2(*(const __half2*)&hv[k].x);
                    float2 f23 = __half22float2(*(const __half2*)&hv[k].y);
                    a0 = fmaf(f01.x, pw[k], a0); a1 = fmaf(f01.y, pw[k], a1);
                    a2c = fmaf(f23.x, pw[k], a2c); a3 = fmaf(f23.y, pw[k], a3);
                }
            }
            for (; t < npc; ++t) {
                int idx = 2 * t + slot;
                int s = sSw[idx];
                float pw = myp[idx];
                uint2 hv = *(const uint2*)&H[(size_t)s * 128 + 4 * c];
                float2 f01 = __half22float2(*(const __half2*)&hv.x);
                float2 f23 = __half22float2(*(const __half2*)&hv.y);
                a0 = fmaf(f01.x, pw, a0); a1 = fmaf(f01.y, pw, a1);
                a2c = fmaf(f23.x, pw, a2c); a3 = fmaf(f23.y, pw, a3);
            }
        } else {
            // rare fallback: slot s lanes process edges s0+slot, s0+slot+2, ...
            const float advh = myh ? adv.y : adv.x;
            for (int i = s0 + slot; i < s1; i += 2) {
                int s = csr_src[i];
                float e = AS[(size_t)s * 2 + myh] + advh;
                e = e > 0.f ? e : NEG_SLOPE * e;
                float pw = __expf(e);
                uint2 hv = *(const uint2*)&H[(size_t)s * 128 + 4 * c];
                float2 f01 = __half22float2(*(const __half2*)&hv.x);
                float2 f23 = __half22float2(*(const __half2*)&hv.y);
                a0 = fmaf(f01.x, pw, a0); a1 = fmaf(f01.y, pw, a1);
                a2c = fmaf(f23.x, pw, a2c); a3 = fmaf(f23.y, pw, a3);
            }
        }
        // combine the two edge slots
        a0 += __shfl_xor(a0, 32, 64);
        a1 += __shfl_xor(a1, 32, 64);
        a2c += __shfl_xor(a2c, 32, 64);
        a3 += __shfl_xor(a3, 32, 64);
        if (lane < 32) {
            float4 o;
            o.x = a0 * myinv + b4.x; o.y = a1 * myinv + b4.y;
            o.z = a2c * myinv + b4.z; o.w = a3 * myinv + b4.w;
            if (do_relu) {
                o.x = fmaxf(o.x, 0.f); o.y = fmaxf(o.y, 0.f);
                o.z = fmaxf(o.z, 0.f); o.w = fmaxf(o.w, 0.f);
            }
            *(float4*)&Out[(size_t)n * 128 + 4 * c] = o;
        }
    }
}

// ---------- fused GAT per-dst, heads=1, fp32 H (final layer) ----------
__global__ __launch_bounds__(256) void gat_csr1(const int* __restrict__ offs,
                                                const int* __restrict__ csr_src,
                                                const float* __restrict__ AS,
                                                const float* __restrict__ AD,
                                                const float* __restrict__ H,
                                                const float* __restrict__ bias,
                                                float* __restrict__ Out,
                                                int N, int do_relu) {
    __shared__ int   sS[4][64];
    __shared__ float sP[4][64];
    const int lane = threadIdx.x & 63;
    const int w = threadIdx.x >> 6;
    const int wid = (int)((blockIdx.x * blockDim.x + threadIdx.x) >> 6);
    const int nw = (int)((gridDim.x * blockDim.x) >> 6);
    const int c = lane & 31;     // channels 2c, 2c+1
    const int slot = lane >> 5;
    int* const sSw = &sS[w][0];
    float* const sPw = &sP[w][0];
    const float2 b2 = *(const float2*)&bias[2 * c];

    for (int n = wid; n < N; n += nw) {
        const int s0 = offs[n], s1 = offs[n + 1];
        const int deg = s1 - s0;
        const float adv0 = AD[n];
        float dn0 = 0.f, p0 = 0.f;
        int sreg = 0;
        for (int i = s0 + lane; i < s1; i += 64) {
            int s = csr_src[i];
            float e0 = AS[s] + adv0;
            e0 = e0 > 0.f ? e0 : NEG_SLOPE * e0;
            float pe0 = __expf(e0);
            dn0 += pe0;
            if (i == s0 + lane) { sreg = s; p0 = pe0; }
        }
        for (int o = 1; o < 64; o <<= 1) dn0 += __shfl_xor(dn0, o, 64);
        const float inv0 = 1.f / (dn0 + EPSF);

        float a0 = 0.f, a1 = 0.f;
        if (deg <= 64) {
            sSw[lane] = sreg;
            sPw[lane] = p0;
            const int npc = (deg + 1) >> 1;
            int t = 0;
            for (; t + 8 <= npc; t += 8) {
                int ss[8]; float pw[8]; float2 hv[8];
#pragma unroll
                for (int k = 0; k < 8; ++k) {
                    int idx = 2 * (t + k) + slot;
                    ss[k] = sSw[idx];
                    pw[k] = sPw[idx];
                }
#pragma unroll
                for (int k = 0; k < 8; ++k)
                    hv[k] = *(const float2*)&H[(size_t)ss[k] * 64 + 2 * c];
#pragma unroll
                for (int k = 0; k < 8; ++k) {
                    a0 = fmaf(hv[k].x, pw[k], a0);
                    a1 = fmaf(hv[k].y, pw[k], a1);
                }
            }
            for (; t < npc; ++t) {
                int idx = 2 * t + slot;
                int s = sSw[idx];
                float pw = sPw[idx];
                float2 hv = *(const float2*)&H[(size_t)s * 64 + 2 * c];
                a0 = fmaf(hv.x, pw, a0);
                a1 = fmaf(hv.y, pw, a1);
            }
        } else {
            for (int i = s0 + slot; i < s1; i += 2) {
                int s = csr_src[i];
                float e = AS[s] + adv0;
                e = e > 0.f ? e : NEG_SLOPE * e;
                float pw = __expf(e);
                float2 hv = *(const float2*)&H[(size_t)s * 64 + 2 * c];
                a0 = fmaf(hv.x, pw, a0);
                a1 = fmaf(hv.y, pw, a1);
            }
        }
        a0 += __shfl_xor(a0, 32, 64);
        a1 += __shfl_xor(a1, 32, 64);
        if (lane < 32) {
            float2 o;
            o.x = a0 * inv0 + b2.x;
            o.y = a1 * inv0 + b2.y;
            if (do_relu) { o.x = fmaxf(o.x, 0.f); o.y = fmaxf(o.y, 0.f); }
            *(float2*)&Out[(size_t)n * 64 + 2 * c] = o;
        }
    }
}

extern "C" void kernel_launch(void* const* d_in, const int* in_sizes, int n_in,
                              void* d_out, int out_size, void* d_ws, size_t ws_size,
                              hipStream_t stream) {
    const float* x   = (const float*)d_in[0];
    const int*   ei  = (const int*)d_in[1];
    const float* W0  = (const float*)d_in[2];
    const float* as0 = (const float*)d_in[3];
    const float* ad0 = (const float*)d_in[4];
    const float* b0  = (const float*)d_in[5];
    const float* W1  = (const float*)d_in[6];
    const float* as1 = (const float*)d_in[7];
    const float* ad1 = (const float*)d_in[8];
    const float* b1  = (const float*)d_in[9];
    const float* W2  = (const float*)d_in[10];
    const float* as2 = (const float*)d_in[11];
    const float* ad2 = (const float*)d_in[12];
    const float* b2  = (const float*)d_in[13];

    const int N = in_sizes[0] / 128;
    const int E_raw = in_sizes[1] / 2;
    const int E = E_raw + N;

    char* ws = (char*)d_ws;
    size_t off = 0;
    auto alloc = [&](size_t bytes) {
        void* p = ws + off;
        off = (off + bytes + 255) & ~(size_t)255;
        return p;
    };
    float* hbuf = (float*)alloc((size_t)N * 128 * 4);
    float* obuf = (float*)alloc((size_t)N * 128 * 4);
    float* asb  = (float*)alloc((size_t)N * 2 * 4);
    float* adb  = (float*)alloc((size_t)N * 2 * 4);
    int*   cnt  = (int*)alloc((size_t)N * 4);
    int*   offs = (int*)alloc((size_t)(N + 1) * 4);
    int*   curs = (int*)alloc((size_t)N * 4);
    int*   bsum = (int*)alloc(1024);
    int* csr_src = (int*)alloc((size_t)E * 4);
    __half* hh = (__half*)hbuf;
    (void)ws_size; (void)n_in; (void)out_size;

    // ---- build CSR grouped by dst (reused by all 3 layers) ----
    const int nb = (N + 255) / 256;
    hipMemsetAsync(cnt, 0, (size_t)N * 4, stream);
    hist_kernel<<<1024, 256, 0, stream>>>(ei, E_raw, N, cnt);
    scan_block<<<nb, 256, 0, stream>>>(cnt, offs, bsum, N);
    scan_bsum<<<1, 256, 0, stream>>>(bsum, nb);
    scan_add<<<nb, 256, 0, stream>>>(offs, bsum, N, E);
    hipMemcpyAsync(curs, offs, (size_t)N * 4, hipMemcpyDeviceToDevice, stream);
    scatter_edges<<<1024, 256, 0, stream>>>(ei, E_raw, N, curs, csr_src);

    const int gemm_blocks = (N + 63) / 64;
    const int gat_blocks = (N * 64 + 255) / 256;

    // Layer 0: x -> obuf (relu)
    gemm_fused<128, 2, true><<<gemm_blocks, 256, 0, stream>>>(x, W0, as0, ad0, nullptr, hh, asb, adb, N);
    gat_csr2<<<gat_blocks, 256, 0, stream>>>(offs, csr_src, asb, adb, hh, b0, obuf, N, 1);
    // Layer 1: obuf -> obuf
    gemm_fused<128, 2, true><<<gemm_blocks, 256, 0, stream>>>(obuf, W1, as1, ad1, nullptr, hh, asb, adb, N);
    gat_csr2<<<gat_blocks, 256, 0, stream>>>(offs, csr_src, asb, adb, hh, b1, obuf, N, 1);
    // Layer 2: obuf -> d_out (heads=1, fp32 path, no relu)
    gemm_fused<64, 1, false><<<gemm_blocks, 256, 0, stream>>>(obuf, W2, as2, ad2, hbuf, nullptr, asb, adb, N);
    gat_csr1<<<gat_blocks, 256, 0, stream>>>(offs, csr_src, asb, adb, hbuf, b2, (float*)d_out, N, 0);
}

// Round 6
// 299.045 us; speedup vs baseline: 5.3500x; 1.0486x over previous
//
#include <hip/hip_runtime.h>
#include <hip/hip_fp16.h>

#define NEG_SLOPE 0.2f
#define EPSF 1e-16f

// ---------- GEMM + fused alpha epilogue ----------
template<int BN, int HEADS, bool OUTH>
__global__ __launch_bounds__(256) void gemm_fused(const float* __restrict__ X,
                                                  const float* __restrict__ W,
                                                  const float* __restrict__ asrc,
                                                  const float* __restrict__ adst,
                                                  float* __restrict__ OutF,
                                                  __half* __restrict__ OutH,
                                                  float* __restrict__ AS,
                                                  float* __restrict__ AD, int N) {
    constexpr int BM = 64, BK = 32, K = 128;
    constexpr int TN = BN / 16;  // 8 (BN=128) or 4 (BN=64)
    __shared__ float Xs[BM][BK + 4];
    __shared__ float Ws[BK][BN];
    const int tid = threadIdx.x;
    const int tx = tid & 15, ty = tid >> 4;
    const int row0 = blockIdx.x * BM;

    float acc[4][TN];
#pragma unroll
    for (int i = 0; i < 4; ++i)
#pragma unroll
        for (int j = 0; j < TN; ++j) acc[i][j] = 0.f;

    for (int kb = 0; kb < K; kb += BK) {
        __syncthreads();
        for (int idx = tid; idx < BK * (BN / 4); idx += 256) {
            int r = idx / (BN / 4), c4 = idx % (BN / 4);
            ((float4*)&Ws[r][0])[c4] = ((const float4*)&W[(size_t)(kb + r) * BN])[c4];
        }
        for (int t = tid; t < BM * (BK / 4); t += 256) {
            int r = t >> 3, c4 = t & 7;
            int gr = row0 + r;
            float4 v = make_float4(0.f, 0.f, 0.f, 0.f);
            if (gr < N) v = *((const float4*)&X[(size_t)gr * K + kb + c4 * 4]);
            Xs[r][c4 * 4 + 0] = v.x; Xs[r][c4 * 4 + 1] = v.y;
            Xs[r][c4 * 4 + 2] = v.z; Xs[r][c4 * 4 + 3] = v.w;
        }
        __syncthreads();
#pragma unroll
        for (int k = 0; k < BK; ++k) {
            float xr[4];
#pragma unroll
            for (int i = 0; i < 4; ++i) xr[i] = Xs[ty * 4 + i][k];
            float wv[TN];
#pragma unroll
            for (int j4 = 0; j4 < TN / 4; ++j4) {
                float4 w4 = ((float4*)&Ws[k][0])[tx * (TN / 4) + j4];
                wv[j4 * 4 + 0] = w4.x; wv[j4 * 4 + 1] = w4.y;
                wv[j4 * 4 + 2] = w4.z; wv[j4 * 4 + 3] = w4.w;
            }
#pragma unroll
            for (int i = 0; i < 4; ++i)
#pragma unroll
                for (int j = 0; j < TN; ++j) acc[i][j] = fmaf(xr[i], wv[j], acc[i][j]);
        }
    }

    float av[TN], dv[TN];
#pragma unroll
    for (int j = 0; j < TN; ++j) { av[j] = asrc[tx * TN + j]; dv[j] = adst[tx * TN + j]; }

#pragma unroll
    for (int i = 0; i < 4; ++i) {
        int gr = row0 + ty * 4 + i;
        if (gr >= N) continue;
        if (OUTH) {
            __half2 hp[TN / 2];
#pragma unroll
            for (int j2 = 0; j2 < TN / 2; ++j2)
                hp[j2] = __floats2half2_rn(acc[i][j2 * 2], acc[i][j2 * 2 + 1]);
            if (TN == 8)
                *((uint4*)&OutH[(size_t)gr * BN + tx * TN]) = *(uint4*)hp;
            else
                *((uint2*)&OutH[(size_t)gr * BN + tx * TN]) = *(uint2*)hp;
        } else {
#pragma unroll
            for (int j4 = 0; j4 < TN / 4; ++j4) {
                float4 o4 = make_float4(acc[i][j4 * 4 + 0], acc[i][j4 * 4 + 1],
                                        acc[i][j4 * 4 + 2], acc[i][j4 * 4 + 3]);
                *((float4*)&OutF[(size_t)gr * BN + tx * TN + j4 * 4]) = o4;
            }
        }
        float ps = 0.f, pd = 0.f;
#pragma unroll
        for (int j = 0; j < TN; ++j) { ps = fmaf(acc[i][j], av[j], ps); pd = fmaf(acc[i][j], dv[j], pd); }
        if (HEADS == 2) {
            for (int o = 1; o < 8; o <<= 1) { ps += __shfl_xor(ps, o, 64); pd += __shfl_xor(pd, o, 64); }
            if ((tx & 7) == 0) { AS[gr * 2 + (tx >> 3)] = ps; AD[gr * 2 + (tx >> 3)] = pd; }
        } else {
            for (int o = 1; o < 16; o <<= 1) { ps += __shfl_xor(ps, o, 64); pd += __shfl_xor(pd, o, 64); }
            if (tx == 0) { AS[gr] = ps; AD[gr] = pd; }
        }
    }
}

// ---------- CSR build ----------
__global__ void hist_kernel(const int* __restrict__ ei, int E_raw, int N,
                            int* __restrict__ cnt) {
    const int E = E_raw + N;
    for (int e = blockIdx.x * blockDim.x + threadIdx.x; e < E; e += gridDim.x * blockDim.x) {
        int d = (e < E_raw) ? ei[E_raw + e] : e - E_raw;
        atomicAdd(&cnt[d], 1);
    }
}

__global__ __launch_bounds__(256) void scan_block(const int* __restrict__ cnt,
                                                  int* __restrict__ offs,
                                                  int* __restrict__ bsum, int N) {
    __shared__ int wsum[4];
    const int i = blockIdx.x * 256 + threadIdx.x;
    const int lane = threadIdx.x & 63, w = threadIdx.x >> 6;
    int v = (i < N) ? cnt[i] : 0;
    int incl = v;
    for (int o = 1; o < 64; o <<= 1) {
        int t = __shfl_up(incl, o, 64);
        if (lane >= o) incl += t;
    }
    if (lane == 63) wsum[w] = incl;
    __syncthreads();
    int prefix = 0;
    for (int k = 0; k < w; ++k) prefix += wsum[k];
    if (i < N) offs[i] = prefix + incl - v;
    if (threadIdx.x == 255) bsum[blockIdx.x] = prefix + incl;
}

__global__ __launch_bounds__(256) void scan_bsum(int* __restrict__ bsum, int nb) {
    __shared__ int wsum[4];
    const int lane = threadIdx.x & 63, w = threadIdx.x >> 6;
    int v = (threadIdx.x < nb) ? bsum[threadIdx.x] : 0;
    int incl = v;
    for (int o = 1; o < 64; o <<= 1) {
        int t = __shfl_up(incl, o, 64);
        if (lane >= o) incl += t;
    }
    if (lane == 63) wsum[w] = incl;
    __syncthreads();
    int prefix = 0;
    for (int k = 0; k < w; ++k) prefix += wsum[k];
    if (threadIdx.x < nb) bsum[threadIdx.x] = prefix + incl - v;
}

__global__ void scan_add(int* __restrict__ offs, const int* __restrict__ bsum,
                         int N, int E) {
    const int i = blockIdx.x * 256 + threadIdx.x;
    if (i < N) offs[i] += bsum[blockIdx.x];
    if (i == 0) offs[N] = E;
}

// XCD-partitioned scatter: blocks with blockIdx%8==k handle dst range k.
// Under round-robin block->XCD dispatch this keeps each csr_src region's
// lines in ONE XCD's L2 (full-line writebacks instead of 64B-per-4B-store
// cross-XCD ping-pong). Correct regardless of the actual mapping.
__global__ void scatter_edges_part(const int* __restrict__ ei, int E_raw, int N,
                                   int* __restrict__ curs, int* __restrict__ csr_src) {
    const int NPART = 8;
    const int part = blockIdx.x & (NPART - 1);
    const int gblocks = gridDim.x >> 3;
    const int grank = blockIdx.x >> 3;
    const int tid = grank * blockDim.x + threadIdx.x;
    const int nthr = gblocks * blockDim.x;
    const int E = E_raw + N;
    const int dlo = (int)(((long long)N * part) / NPART);
    const int dhi = (int)(((long long)N * (part + 1)) / NPART);
    for (int e = tid; e < E; e += nthr) {
        int d = (e < E_raw) ? ei[E_raw + e] : e - E_raw;
        if (d >= dlo && d < dhi) {
            int s = (e < E_raw) ? ei[e] : d;
            int pos = atomicAdd(&curs[d], 1);
            csr_src[pos] = s;
        }
    }
}

// ---------- fused GAT per-dst, heads=2, fp16 H ----------
__global__ __launch_bounds__(256) void gat_csr2(const int* __restrict__ offs,
                                                const int* __restrict__ csr_src,
                                                const float* __restrict__ AS,
                                                const float* __restrict__ AD,
                                                const __half* __restrict__ H,
                                                const float* __restrict__ bias,
                                                float* __restrict__ Out,
                                                int N, int do_relu) {
    __shared__ int   sS[4][64];
    __shared__ float sP0[4][64];
    __shared__ float sP1[4][64];
    const int lane = threadIdx.x & 63;
    const int w = threadIdx.x >> 6;
    const int wid = (int)((blockIdx.x * blockDim.x + threadIdx.x) >> 6);
    const int nw = (int)((gridDim.x * blockDim.x) >> 6);
    const int c = lane & 31;      // channel group: channels 4c..4c+3
    const int slot = lane >> 5;   // which of the 2 in-flight edges
    const int myh = c >> 4;       // head owning my channels
    int* const sSw = &sS[w][0];
    const float* const myp = myh ? &sP1[w][0] : &sP0[w][0];
    const float4 b4 = *(const float4*)&bias[4 * c];

    for (int n = wid; n < N; n += nw) {
        const int s0 = offs[n], s1 = offs[n + 1];
        const int deg = s1 - s0;
        const float2 adv = *(const float2*)&AD[(size_t)n * 2];
        float dn0 = 0.f, dn1 = 0.f, p0 = 0.f, p1 = 0.f;
        int sreg = 0;
        for (int i = s0 + lane; i < s1; i += 64) {
            int s = csr_src[i];
            float2 a2 = *(const float2*)&AS[(size_t)s * 2];
            float e0 = a2.x + adv.x, e1 = a2.y + adv.y;
            e0 = e0 > 0.f ? e0 : NEG_SLOPE * e0;
            e1 = e1 > 0.f ? e1 : NEG_SLOPE * e1;
            float pe0 = __expf(e0), pe1 = __expf(e1);
            dn0 += pe0; dn1 += pe1;
            if (i == s0 + lane) { sreg = s; p0 = pe0; p1 = pe1; }
        }
        for (int o = 1; o < 64; o <<= 1) {
            dn0 += __shfl_xor(dn0, o, 64);
            dn1 += __shfl_xor(dn1, o, 64);
        }
        const float myinv = 1.f / ((myh ? dn1 : dn0) + EPSF);

        float a0 = 0.f, a1 = 0.f, a2c = 0.f, a3 = 0.f;
        if (deg <= 64) {
            sSw[lane] = sreg;
            sP0[w][lane] = p0;
            sP1[w][lane] = p1;
            const int npc = (deg + 1) >> 1;
            int t = 0;
            for (; t + 8 <= npc; t += 8) {
                int ss[8]; float pw[8]; uint2 hv[8];
#pragma unroll
                for (int k = 0; k < 8; ++k) {
                    int idx = 2 * (t + k) + slot;
                    ss[k] = sSw[idx];
                    pw[k] = myp[idx];
                }
#pragma unroll
                for (int k = 0; k < 8; ++k)
                    hv[k] = *(const uint2*)&H[(size_t)ss[k] * 128 + 4 * c];
#pragma unroll
                for (int k = 0; k < 8; ++k) {
                    float2 f01 = __half22float2(*(const __half2*)&hv[k].x);
                    float2 f23 = __half22float2(*(const __half2*)&hv[k].y);
                    a0 = fmaf(f01.x, pw[k], a0); a1 = fmaf(f01.y, pw[k], a1);
                    a2c = fmaf(f23.x, pw[k], a2c); a3 = fmaf(f23.y, pw[k], a3);
                }
            }
            for (; t < npc; ++t) {
                int idx = 2 * t + slot;
                int s = sSw[idx];
                float pw = myp[idx];
                uint2 hv = *(const uint2*)&H[(size_t)s * 128 + 4 * c];
                float2 f01 = __half22float2(*(const __half2*)&hv.x);
                float2 f23 = __half22float2(*(const __half2*)&hv.y);
                a0 = fmaf(f01.x, pw, a0); a1 = fmaf(f01.y, pw, a1);
                a2c = fmaf(f23.x, pw, a2c); a3 = fmaf(f23.y, pw, a3);
            }
        } else {
            const float advh = myh ? adv.y : adv.x;
            for (int i = s0 + slot; i < s1; i += 2) {
                int s = csr_src[i];
                float e = AS[(size_t)s * 2 + myh] + advh;
                e = e > 0.f ? e : NEG_SLOPE * e;
                float pw = __expf(e);
                uint2 hv = *(const uint2*)&H[(size_t)s * 128 + 4 * c];
                float2 f01 = __half22float2(*(const __half2*)&hv.x);
                float2 f23 = __half22float2(*(const __half2*)&hv.y);
                a0 = fmaf(f01.x, pw, a0); a1 = fmaf(f01.y, pw, a1);
                a2c = fmaf(f23.x, pw, a2c); a3 = fmaf(f23.y, pw, a3);
            }
        }
        a0 += __shfl_xor(a0, 32, 64);
        a1 += __shfl_xor(a1, 32, 64);
        a2c += __shfl_xor(a2c, 32, 64);
        a3 += __shfl_xor(a3, 32, 64);
        if (lane < 32) {
            float4 o;
            o.x = a0 * myinv + b4.x; o.y = a1 * myinv + b4.y;
            o.z = a2c * myinv + b4.z; o.w = a3 * myinv + b4.w;
            if (do_relu) {
                o.x = fmaxf(o.x, 0.f); o.y = fmaxf(o.y, 0.f);
                o.z = fmaxf(o.z, 0.f); o.w = fmaxf(o.w, 0.f);
            }
            *(float4*)&Out[(size_t)n * 128 + 4 * c] = o;
        }
    }
}

// ---------- fused GAT per-dst, heads=1, fp32 H (final layer) ----------
__global__ __launch_bounds__(256) void gat_csr1(const int* __restrict__ offs,
                                                const int* __restrict__ csr_src,
                                                const float* __restrict__ AS,
                                                const float* __restrict__ AD,
                                                const float* __restrict__ H,
                                                const float* __restrict__ bias,
                                                float* __restrict__ Out,
                                                int N, int do_relu) {
    __shared__ int   sS[4][64];
    __shared__ float sP[4][64];
    const int lane = threadIdx.x & 63;
    const int w = threadIdx.x >> 6;
    const int wid = (int)((blockIdx.x * blockDim.x + threadIdx.x) >> 6);
    const int nw = (int)((gridDim.x * blockDim.x) >> 6);
    const int c = lane & 31;
    const int slot = lane >> 5;
    int* const sSw = &sS[w][0];
    float* const sPw = &sP[w][0];
    const float2 b2 = *(const float2*)&bias[2 * c];

    for (int n = wid; n < N; n += nw) {
        const int s0 = offs[n], s1 = offs[n + 1];
        const int deg = s1 - s0;
        const float adv0 = AD[n];
        float dn0 = 0.f, p0 = 0.f;
        int sreg = 0;
        for (int i = s0 + lane; i < s1; i += 64) {
            int s = csr_src[i];
            float e0 = AS[s] + adv0;
            e0 = e0 > 0.f ? e0 : NEG_SLOPE * e0;
            float pe0 = __expf(e0);
            dn0 += pe0;
            if (i == s0 + lane) { sreg = s; p0 = pe0; }
        }
        for (int o = 1; o < 64; o <<= 1) dn0 += __shfl_xor(dn0, o, 64);
        const float inv0 = 1.f / (dn0 + EPSF);

        float a0 = 0.f, a1 = 0.f;
        if (deg <= 64) {
            sSw[lane] = sreg;
            sPw[lane] = p0;
            const int npc = (deg + 1) >> 1;
            int t = 0;
            for (; t + 8 <= npc; t += 8) {
                int ss[8]; float pw[8]; float2 hv[8];
#pragma unroll
                for (int k = 0; k < 8; ++k) {
                    int idx = 2 * (t + k) + slot;
                    ss[k] = sSw[idx];
                    pw[k] = sPw[idx];
                }
#pragma unroll
                for (int k = 0; k < 8; ++k)
                    hv[k] = *(const float2*)&H[(size_t)ss[k] * 64 + 2 * c];
#pragma unroll
                for (int k = 0; k < 8; ++k) {
                    a0 = fmaf(hv[k].x, pw[k], a0);
                    a1 = fmaf(hv[k].y, pw[k], a1);
                }
            }
            for (; t < npc; ++t) {
                int idx = 2 * t + slot;
                int s = sSw[idx];
                float pw = sPw[idx];
                float2 hv = *(const float2*)&H[(size_t)s * 64 + 2 * c];
                a0 = fmaf(hv.x, pw, a0);
                a1 = fmaf(hv.y, pw, a1);
            }
        } else {
            for (int i = s0 + slot; i < s1; i += 2) {
                int s = csr_src[i];
                float e = AS[s] + adv0;
                e = e > 0.f ? e : NEG_SLOPE * e;
                float pw = __expf(e);
                float2 hv = *(const float2*)&H[(size_t)s * 64 + 2 * c];
                a0 = fmaf(hv.x, pw, a0);
                a1 = fmaf(hv.y, pw, a1);
            }
        }
        a0 += __shfl_xor(a0, 32, 64);
        a1 += __shfl_xor(a1, 32, 64);
        if (lane < 32) {
            float2 o;
            o.x = a0 * inv0 + b2.x;
            o.y = a1 * inv0 + b2.y;
            if (do_relu) { o.x = fmaxf(o.x, 0.f); o.y = fmaxf(o.y, 0.f); }
            *(float2*)&Out[(size_t)n * 64 + 2 * c] = o;
        }
    }
}

extern "C" void kernel_launch(void* const* d_in, const int* in_sizes, int n_in,
                              void* d_out, int out_size, void* d_ws, size_t ws_size,
                              hipStream_t stream) {
    const float* x   = (const float*)d_in[0];
    const int*   ei  = (const int*)d_in[1];
    const float* W0  = (const float*)d_in[2];
    const float* as0 = (const float*)d_in[3];
    const float* ad0 = (const float*)d_in[4];
    const float* b0  = (const float*)d_in[5];
    const float* W1  = (const float*)d_in[6];
    const float* as1 = (const float*)d_in[7];
    const float* ad1 = (const float*)d_in[8];
    const float* b1  = (const float*)d_in[9];
    const float* W2  = (const float*)d_in[10];
    const float* as2 = (const float*)d_in[11];
    const float* ad2 = (const float*)d_in[12];
    const float* b2  = (const float*)d_in[13];

    const int N = in_sizes[0] / 128;
    const int E_raw = in_sizes[1] / 2;
    const int E = E_raw + N;

    char* ws = (char*)d_ws;
    size_t off = 0;
    auto alloc = [&](size_t bytes) {
        void* p = ws + off;
        off = (off + bytes + 255) & ~(size_t)255;
        return p;
    };
    float* hbuf = (float*)alloc((size_t)N * 128 * 4);
    float* obuf = (float*)alloc((size_t)N * 128 * 4);
    float* asb  = (float*)alloc((size_t)N * 2 * 4);
    float* adb  = (float*)alloc((size_t)N * 2 * 4);
    int*   cnt  = (int*)alloc((size_t)N * 4);
    int*   offs = (int*)alloc((size_t)(N + 1) * 4);
    int*   curs = (int*)alloc((size_t)N * 4);
    int*   bsum = (int*)alloc(1024);
    int* csr_src = (int*)alloc((size_t)E * 4);
    __half* hh = (__half*)hbuf;
    (void)ws_size; (void)n_in; (void)out_size;

    // ---- build CSR grouped by dst (reused by all 3 layers) ----
    const int nb = (N + 255) / 256;
    hipMemsetAsync(cnt, 0, (size_t)N * 4, stream);
    hist_kernel<<<2048, 256, 0, stream>>>(ei, E_raw, N, cnt);
    scan_block<<<nb, 256, 0, stream>>>(cnt, offs, bsum, N);
    scan_bsum<<<1, 256, 0, stream>>>(bsum, nb);
    scan_add<<<nb, 256, 0, stream>>>(offs, bsum, N, E);
    hipMemcpyAsync(curs, offs, (size_t)N * 4, hipMemcpyDeviceToDevice, stream);
    scatter_edges_part<<<2048, 256, 0, stream>>>(ei, E_raw, N, curs, csr_src);

    const int gemm_blocks = (N + 63) / 64;
    const int gat_blocks = (N * 64 + 255) / 256;

    // Layer 0: x -> obuf (relu)
    gemm_fused<128, 2, true><<<gemm_blocks, 256, 0, stream>>>(x, W0, as0, ad0, nullptr, hh, asb, adb, N);
    gat_csr2<<<gat_blocks, 256, 0, stream>>>(offs, csr_src, asb, adb, hh, b0, obuf, N, 1);
    // Layer 1: obuf -> obuf
    gemm_fused<128, 2, true><<<gemm_blocks, 256, 0, stream>>>(obuf, W1, as1, ad1, nullptr, hh, asb, adb, N);
    gat_csr2<<<gat_blocks, 256, 0, stream>>>(offs, csr_src, asb, adb, hh, b1, obuf, N, 1);
    // Layer 2: obuf -> d_out (heads=1, fp32 path, no relu)
    gemm_fused<64, 1, false><<<gemm_blocks, 256, 0, stream>>>(obuf, W2, as2, ad2, hbuf, nullptr, asb, adb, N);
    gat_csr1<<<gat_blocks, 256, 0, stream>>>(offs, csr_src, asb, adb, hbuf, b2, (float*)d_out, N, 0);
}

// Round 7
// 291.937 us; speedup vs baseline: 5.4803x; 1.0243x over previous
//
#include <hip/hip_runtime.h>
#include <hip/hip_fp16.h>

#define NEG_SLOPE 0.2f
#define EPSF 1e-16f

// ---------- GEMM + fused alpha epilogue ----------
template<int BN, int HEADS, bool OUTH>
__global__ __launch_bounds__(256) void gemm_fused(const float* __restrict__ X,
                                                  const float* __restrict__ W,
                                                  const float* __restrict__ asrc,
                                                  const float* __restrict__ adst,
                                                  float* __restrict__ OutF,
                                                  __half* __restrict__ OutH,
                                                  float* __restrict__ AS,
                                                  float* __restrict__ AD, int N) {
    constexpr int BM = 64, BK = 32, K = 128;
    constexpr int TN = BN / 16;  // 8 (BN=128) or 4 (BN=64)
    __shared__ float Xs[BM][BK + 4];
    __shared__ float Ws[BK][BN];
    const int tid = threadIdx.x;
    const int tx = tid & 15, ty = tid >> 4;
    const int row0 = blockIdx.x * BM;

    float acc[4][TN];
#pragma unroll
    for (int i = 0; i < 4; ++i)
#pragma unroll
        for (int j = 0; j < TN; ++j) acc[i][j] = 0.f;

    for (int kb = 0; kb < K; kb += BK) {
        __syncthreads();
        for (int idx = tid; idx < BK * (BN / 4); idx += 256) {
            int r = idx / (BN / 4), c4 = idx % (BN / 4);
            ((float4*)&Ws[r][0])[c4] = ((const float4*)&W[(size_t)(kb + r) * BN])[c4];
        }
        for (int t = tid; t < BM * (BK / 4); t += 256) {
            int r = t >> 3, c4 = t & 7;
            int gr = row0 + r;
            float4 v = make_float4(0.f, 0.f, 0.f, 0.f);
            if (gr < N) v = *((const float4*)&X[(size_t)gr * K + kb + c4 * 4]);
            Xs[r][c4 * 4 + 0] = v.x; Xs[r][c4 * 4 + 1] = v.y;
            Xs[r][c4 * 4 + 2] = v.z; Xs[r][c4 * 4 + 3] = v.w;
        }
        __syncthreads();
#pragma unroll
        for (int k = 0; k < BK; ++k) {
            float xr[4];
#pragma unroll
            for (int i = 0; i < 4; ++i) xr[i] = Xs[ty * 4 + i][k];
            float wv[TN];
#pragma unroll
            for (int j4 = 0; j4 < TN / 4; ++j4) {
                float4 w4 = ((float4*)&Ws[k][0])[tx * (TN / 4) + j4];
                wv[j4 * 4 + 0] = w4.x; wv[j4 * 4 + 1] = w4.y;
                wv[j4 * 4 + 2] = w4.z; wv[j4 * 4 + 3] = w4.w;
            }
#pragma unroll
            for (int i = 0; i < 4; ++i)
#pragma unroll
                for (int j = 0; j < TN; ++j) acc[i][j] = fmaf(xr[i], wv[j], acc[i][j]);
        }
    }

    float av[TN], dv[TN];
#pragma unroll
    for (int j = 0; j < TN; ++j) { av[j] = asrc[tx * TN + j]; dv[j] = adst[tx * TN + j]; }

#pragma unroll
    for (int i = 0; i < 4; ++i) {
        int gr = row0 + ty * 4 + i;
        if (gr >= N) continue;
        if (OUTH) {
            __half2 hp[TN / 2];
#pragma unroll
            for (int j2 = 0; j2 < TN / 2; ++j2)
                hp[j2] = __floats2half2_rn(acc[i][j2 * 2], acc[i][j2 * 2 + 1]);
            if (TN == 8)
                *((uint4*)&OutH[(size_t)gr * BN + tx * TN]) = *(uint4*)hp;
            else
                *((uint2*)&OutH[(size_t)gr * BN + tx * TN]) = *(uint2*)hp;
        } else {
#pragma unroll
            for (int j4 = 0; j4 < TN / 4; ++j4) {
                float4 o4 = make_float4(acc[i][j4 * 4 + 0], acc[i][j4 * 4 + 1],
                                        acc[i][j4 * 4 + 2], acc[i][j4 * 4 + 3]);
                *((float4*)&OutF[(size_t)gr * BN + tx * TN + j4 * 4]) = o4;
            }
        }
        float ps = 0.f, pd = 0.f;
#pragma unroll
        for (int j = 0; j < TN; ++j) { ps = fmaf(acc[i][j], av[j], ps); pd = fmaf(acc[i][j], dv[j], pd); }
        if (HEADS == 2) {
            for (int o = 1; o < 8; o <<= 1) { ps += __shfl_xor(ps, o, 64); pd += __shfl_xor(pd, o, 64); }
            if ((tx & 7) == 0) { AS[gr * 2 + (tx >> 3)] = ps; AD[gr * 2 + (tx >> 3)] = pd; }
        } else {
            for (int o = 1; o < 16; o <<= 1) { ps += __shfl_xor(ps, o, 64); pd += __shfl_xor(pd, o, 64); }
            if (tx == 0) { AS[gr] = ps; AD[gr] = pd; }
        }
    }
}

// ---------- CSR build ----------
__global__ void hist_kernel(const int* __restrict__ ei, int E_raw, int N,
                            int* __restrict__ cnt) {
    const int E = E_raw + N;
    for (int e = blockIdx.x * blockDim.x + threadIdx.x; e < E; e += gridDim.x * blockDim.x) {
        int d = (e < E_raw) ? ei[E_raw + e] : e - E_raw;
        atomicAdd(&cnt[d], 1);
    }
}

__global__ __launch_bounds__(256) void scan_block(const int* __restrict__ cnt,
                                                  int* __restrict__ offs,
                                                  int* __restrict__ bsum, int N) {
    __shared__ int wsum[4];
    const int i = blockIdx.x * 256 + threadIdx.x;
    const int lane = threadIdx.x & 63, w = threadIdx.x >> 6;
    int v = (i < N) ? cnt[i] : 0;
    int incl = v;
    for (int o = 1; o < 64; o <<= 1) {
        int t = __shfl_up(incl, o, 64);
        if (lane >= o) incl += t;
    }
    if (lane == 63) wsum[w] = incl;
    __syncthreads();
    int prefix = 0;
    for (int k = 0; k < w; ++k) prefix += wsum[k];
    if (i < N) offs[i] = prefix + incl - v;
    if (threadIdx.x == 255) bsum[blockIdx.x] = prefix + incl;
}

__global__ __launch_bounds__(256) void scan_bsum(int* __restrict__ bsum, int nb) {
    __shared__ int wsum[4];
    const int lane = threadIdx.x & 63, w = threadIdx.x >> 6;
    int v = (threadIdx.x < nb) ? bsum[threadIdx.x] : 0;
    int incl = v;
    for (int o = 1; o < 64; o <<= 1) {
        int t = __shfl_up(incl, o, 64);
        if (lane >= o) incl += t;
    }
    if (lane == 63) wsum[w] = incl;
    __syncthreads();
    int prefix = 0;
    for (int k = 0; k < w; ++k) prefix += wsum[k];
    if (threadIdx.x < nb) bsum[threadIdx.x] = prefix + incl - v;
}

__global__ void scan_add(int* __restrict__ offs, const int* __restrict__ bsum,
                         int N, int E) {
    const int i = blockIdx.x * 256 + threadIdx.x;
    if (i < N) offs[i] += bsum[blockIdx.x];
    if (i == 0) offs[N] = E;
}

// XCD-partitioned scatter (see R5 notes): keeps each csr_src region's lines
// in one XCD's L2 -> full-line writebacks. Correct for any block->XCD map.
__global__ void scatter_edges_part(const int* __restrict__ ei, int E_raw, int N,
                                   int* __restrict__ curs, int* __restrict__ csr_src) {
    const int NPART = 8;
    const int part = blockIdx.x & (NPART - 1);
    const int gblocks = gridDim.x >> 3;
    const int grank = blockIdx.x >> 3;
    const int tid = grank * blockDim.x + threadIdx.x;
    const int nthr = gblocks * blockDim.x;
    const int E = E_raw + N;
    const int dlo = (int)(((long long)N * part) / NPART);
    const int dhi = (int)(((long long)N * (part + 1)) / NPART);
    for (int e = tid; e < E; e += nthr) {
        int d = (e < E_raw) ? ei[E_raw + e] : e - E_raw;
        if (d >= dlo && d < dhi) {
            int s = (e < E_raw) ? ei[e] : d;
            int pos = atomicAdd(&curs[d], 1);
            csr_src[pos] = s;
        }
    }
}

// ---------- fused GAT per-dst, heads=2, fp16 H ----------
// Wave per dst node. Aggregate: 4 edge slots x 16 lanes, 8 channels/lane
// (uint4 = 16B), 4-deep batches -> 16 edge-gathers in flight per wave.
__global__ __launch_bounds__(256) void gat_csr2(const int* __restrict__ offs,
                                                const int* __restrict__ csr_src,
                                                const float* __restrict__ AS,
                                                const float* __restrict__ AD,
                                                const __half* __restrict__ H,
                                                const float* __restrict__ bias,
                                                float* __restrict__ Out,
                                                int N, int do_relu) {
    __shared__ int   sS[4][64];
    __shared__ float sP0[4][64];
    __shared__ float sP1[4][64];
    const int lane = threadIdx.x & 63;
    const int w = threadIdx.x >> 6;
    const int wid = (int)((blockIdx.x * blockDim.x + threadIdx.x) >> 6);
    const int nw = (int)((gridDim.x * blockDim.x) >> 6);
    const int c = lane & 15;      // channels 8c..8c+7
    const int slot = lane >> 4;   // 4 edge slots
    const int myh = c >> 3;       // head owning my channels
    int* const sSw = &sS[w][0];
    const float* const myp = myh ? &sP1[w][0] : &sP0[w][0];
    const float4 bA = *(const float4*)&bias[8 * c];
    const float4 bB = *(const float4*)&bias[8 * c + 4];

    for (int n = wid; n < N; n += nw) {
        const int s0 = offs[n], s1 = offs[n + 1];
        const int deg = s1 - s0;
        const float2 adv = *(const float2*)&AD[(size_t)n * 2];
        float dn0 = 0.f, dn1 = 0.f, p0 = 0.f, p1 = 0.f;
        int sreg = 0;
        for (int i = s0 + lane; i < s1; i += 64) {
            int s = csr_src[i];
            float2 a2 = *(const float2*)&AS[(size_t)s * 2];
            float e0 = a2.x + adv.x, e1 = a2.y + adv.y;
            e0 = e0 > 0.f ? e0 : NEG_SLOPE * e0;
            e1 = e1 > 0.f ? e1 : NEG_SLOPE * e1;
            float pe0 = __expf(e0), pe1 = __expf(e1);
            dn0 += pe0; dn1 += pe1;
            if (i == s0 + lane) { sreg = s; p0 = pe0; p1 = pe1; }
        }
        for (int o = 1; o < 64; o <<= 1) {
            dn0 += __shfl_xor(dn0, o, 64);
            dn1 += __shfl_xor(dn1, o, 64);
        }
        const float myinv = 1.f / ((myh ? dn1 : dn0) + EPSF);

        float a[8];
#pragma unroll
        for (int j = 0; j < 8; ++j) a[j] = 0.f;
        if (deg <= 64) {
            sSw[lane] = sreg;
            sP0[w][lane] = p0;
            sP1[w][lane] = p1;
            const int npc = (deg + 3) >> 2;   // quads; phantom edges have p=0
            int t = 0;
            for (; t + 4 <= npc; t += 4) {
                int ss[4]; float pw[4]; uint4 hv[4];
#pragma unroll
                for (int k = 0; k < 4; ++k) {
                    int idx = 4 * (t + k) + slot;
                    ss[k] = sSw[idx];
                    pw[k] = myp[idx];
                }
#pragma unroll
                for (int k = 0; k < 4; ++k)
                    hv[k] = *(const uint4*)&H[(size_t)ss[k] * 128 + 8 * c];
#pragma unroll
                for (int k = 0; k < 4; ++k) {
                    const __half2* h2 = (const __half2*)&hv[k];
#pragma unroll
                    for (int j = 0; j < 4; ++j) {
                        float2 f = __half22float2(h2[j]);
                        a[2 * j]     = fmaf(f.x, pw[k], a[2 * j]);
                        a[2 * j + 1] = fmaf(f.y, pw[k], a[2 * j + 1]);
                    }
                }
            }
            for (; t < npc; ++t) {
                int idx = 4 * t + slot;
                int s = sSw[idx];
                float pw = myp[idx];
                uint4 hv = *(const uint4*)&H[(size_t)s * 128 + 8 * c];
                const __half2* h2 = (const __half2*)&hv;
#pragma unroll
                for (int j = 0; j < 4; ++j) {
                    float2 f = __half22float2(h2[j]);
                    a[2 * j]     = fmaf(f.x, pw, a[2 * j]);
                    a[2 * j + 1] = fmaf(f.y, pw, a[2 * j + 1]);
                }
            }
        } else {
            const float advh = myh ? adv.y : adv.x;
            for (int i = s0 + slot; i < s1; i += 4) {
                int s = csr_src[i];
                float e = AS[(size_t)s * 2 + myh] + advh;
                e = e > 0.f ? e : NEG_SLOPE * e;
                float pw = __expf(e);
                uint4 hv = *(const uint4*)&H[(size_t)s * 128 + 8 * c];
                const __half2* h2 = (const __half2*)&hv;
#pragma unroll
                for (int j = 0; j < 4; ++j) {
                    float2 f = __half22float2(h2[j]);
                    a[2 * j]     = fmaf(f.x, pw, a[2 * j]);
                    a[2 * j + 1] = fmaf(f.y, pw, a[2 * j + 1]);
                }
            }
        }
        // combine the 4 edge slots
#pragma unroll
        for (int j = 0; j < 8; ++j) {
            a[j] += __shfl_xor(a[j], 16, 64);
            a[j] += __shfl_xor(a[j], 32, 64);
        }
        if (lane < 16) {
            float4 oA, oB;
            oA.x = a[0] * myinv + bA.x; oA.y = a[1] * myinv + bA.y;
            oA.z = a[2] * myinv + bA.z; oA.w = a[3] * myinv + bA.w;
            oB.x = a[4] * myinv + bB.x; oB.y = a[5] * myinv + bB.y;
            oB.z = a[6] * myinv + bB.z; oB.w = a[7] * myinv + bB.w;
            if (do_relu) {
                oA.x = fmaxf(oA.x, 0.f); oA.y = fmaxf(oA.y, 0.f);
                oA.z = fmaxf(oA.z, 0.f); oA.w = fmaxf(oA.w, 0.f);
                oB.x = fmaxf(oB.x, 0.f); oB.y = fmaxf(oB.y, 0.f);
                oB.z = fmaxf(oB.z, 0.f); oB.w = fmaxf(oB.w, 0.f);
            }
            *(float4*)&Out[(size_t)n * 128 + 8 * c] = oA;
            *(float4*)&Out[(size_t)n * 128 + 8 * c + 4] = oB;
        }
    }
}

// ---------- fused GAT per-dst, heads=1, fp32 H (final layer) ----------
__global__ __launch_bounds__(256) void gat_csr1(const int* __restrict__ offs,
                                                const int* __restrict__ csr_src,
                                                const float* __restrict__ AS,
                                                const float* __restrict__ AD,
                                                const float* __restrict__ H,
                                                const float* __restrict__ bias,
                                                float* __restrict__ Out,
                                                int N, int do_relu) {
    __shared__ int   sS[4][64];
    __shared__ float sP[4][64];
    const int lane = threadIdx.x & 63;
    const int w = threadIdx.x >> 6;
    const int wid = (int)((blockIdx.x * blockDim.x + threadIdx.x) >> 6);
    const int nw = (int)((gridDim.x * blockDim.x) >> 6);
    const int c = lane & 15;     // channels 4c..4c+3
    const int slot = lane >> 4;  // 4 edge slots
    int* const sSw = &sS[w][0];
    float* const sPw = &sP[w][0];
    const float4 b4 = *(const float4*)&bias[4 * c];

    for (int n = wid; n < N; n += nw) {
        const int s0 = offs[n], s1 = offs[n + 1];
        const int deg = s1 - s0;
        const float adv0 = AD[n];
        float dn0 = 0.f, p0 = 0.f;
        int sreg = 0;
        for (int i = s0 + lane; i < s1; i += 64) {
            int s = csr_src[i];
            float e0 = AS[s] + adv0;
            e0 = e0 > 0.f ? e0 : NEG_SLOPE * e0;
            float pe0 = __expf(e0);
            dn0 += pe0;
            if (i == s0 + lane) { sreg = s; p0 = pe0; }
        }
        for (int o = 1; o < 64; o <<= 1) dn0 += __shfl_xor(dn0, o, 64);
        const float inv0 = 1.f / (dn0 + EPSF);

        float a[4];
#pragma unroll
        for (int j = 0; j < 4; ++j) a[j] = 0.f;
        if (deg <= 64) {
            sSw[lane] = sreg;
            sPw[lane] = p0;
            const int npc = (deg + 3) >> 2;
            int t = 0;
            for (; t + 4 <= npc; t += 4) {
                int ss[4]; float pw[4]; float4 hv[4];
#pragma unroll
                for (int k = 0; k < 4; ++k) {
                    int idx = 4 * (t + k) + slot;
                    ss[k] = sSw[idx];
                    pw[k] = sPw[idx];
                }
#pragma unroll
                for (int k = 0; k < 4; ++k)
                    hv[k] = *(const float4*)&H[(size_t)ss[k] * 64 + 4 * c];
#pragma unroll
                for (int k = 0; k < 4; ++k) {
                    a[0] = fmaf(hv[k].x, pw[k], a[0]);
                    a[1] = fmaf(hv[k].y, pw[k], a[1]);
                    a[2] = fmaf(hv[k].z, pw[k], a[2]);
                    a[3] = fmaf(hv[k].w, pw[k], a[3]);
                }
            }
            for (; t < npc; ++t) {
                int idx = 4 * t + slot;
                int s = sSw[idx];
                float pw = sPw[idx];
                float4 hv = *(const float4*)&H[(size_t)s * 64 + 4 * c];
                a[0] = fmaf(hv.x, pw, a[0]);
                a[1] = fmaf(hv.y, pw, a[1]);
                a[2] = fmaf(hv.z, pw, a[2]);
                a[3] = fmaf(hv.w, pw, a[3]);
            }
        } else {
            for (int i = s0 + slot; i < s1; i += 4) {
                int s = csr_src[i];
                float e = AS[s] + adv0;
                e = e > 0.f ? e : NEG_SLOPE * e;
                float pw = __expf(e);
                float4 hv = *(const float4*)&H[(size_t)s * 64 + 4 * c];
                a[0] = fmaf(hv.x, pw, a[0]);
                a[1] = fmaf(hv.y, pw, a[1]);
                a[2] = fmaf(hv.z, pw, a[2]);
                a[3] = fmaf(hv.w, pw, a[3]);
            }
        }
#pragma unroll
        for (int j = 0; j < 4; ++j) {
            a[j] += __shfl_xor(a[j], 16, 64);
            a[j] += __shfl_xor(a[j], 32, 64);
        }
        if (lane < 16) {
            float4 o;
            o.x = a[0] * inv0 + b4.x;
            o.y = a[1] * inv0 + b4.y;
            o.z = a[2] * inv0 + b4.z;
            o.w = a[3] * inv0 + b4.w;
            if (do_relu) {
                o.x = fmaxf(o.x, 0.f); o.y = fmaxf(o.y, 0.f);
                o.z = fmaxf(o.z, 0.f); o.w = fmaxf(o.w, 0.f);
            }
            *(float4*)&Out[(size_t)n * 64 + 4 * c] = o;
        }
    }
}

extern "C" void kernel_launch(void* const* d_in, const int* in_sizes, int n_in,
                              void* d_out, int out_size, void* d_ws, size_t ws_size,
                              hipStream_t stream) {
    const float* x   = (const float*)d_in[0];
    const int*   ei  = (const int*)d_in[1];
    const float* W0  = (const float*)d_in[2];
    const float* as0 = (const float*)d_in[3];
    const float* ad0 = (const float*)d_in[4];
    const float* b0  = (const float*)d_in[5];
    const float* W1  = (const float*)d_in[6];
    const float* as1 = (const float*)d_in[7];
    const float* ad1 = (const float*)d_in[8];
    const float* b1  = (const float*)d_in[9];
    const float* W2  = (const float*)d_in[10];
    const float* as2 = (const float*)d_in[11];
    const float* ad2 = (const float*)d_in[12];
    const float* b2  = (const float*)d_in[13];

    const int N = in_sizes[0] / 128;
    const int E_raw = in_sizes[1] / 2;
    const int E = E_raw + N;

    char* ws = (char*)d_ws;
    size_t off = 0;
    auto alloc = [&](size_t bytes) {
        void* p = ws + off;
        off = (off + bytes + 255) & ~(size_t)255;
        return p;
    };
    float* hbuf = (float*)alloc((size_t)N * 128 * 4);
    float* obuf = (float*)alloc((size_t)N * 128 * 4);
    float* asb  = (float*)alloc((size_t)N * 2 * 4);
    float* adb  = (float*)alloc((size_t)N * 2 * 4);
    int*   cnt  = (int*)alloc((size_t)N * 4);
    int*   offs = (int*)alloc((size_t)(N + 1) * 4);
    int*   curs = (int*)alloc((size_t)N * 4);
    int*   bsum = (int*)alloc(1024);
    int* csr_src = (int*)alloc((size_t)E * 4);
    __half* hh = (__half*)hbuf;
    (void)ws_size; (void)n_in; (void)out_size;

    // ---- build CSR grouped by dst (reused by all 3 layers) ----
    const int nb = (N + 255) / 256;
    hipMemsetAsync(cnt, 0, (size_t)N * 4, stream);
    hist_kernel<<<2048, 256, 0, stream>>>(ei, E_raw, N, cnt);
    scan_block<<<nb, 256, 0, stream>>>(cnt, offs, bsum, N);
    scan_bsum<<<1, 256, 0, stream>>>(bsum, nb);
    scan_add<<<nb, 256, 0, stream>>>(offs, bsum, N, E);
    hipMemcpyAsync(curs, offs, (size_t)N * 4, hipMemcpyDeviceToDevice, stream);
    scatter_edges_part<<<2048, 256, 0, stream>>>(ei, E_raw, N, curs, csr_src);

    const int gemm_blocks = (N + 63) / 64;
    const int gat_blocks = (N * 64 + 255) / 256;

    // Layer 0: x -> obuf (relu)
    gemm_fused<128, 2, true><<<gemm_blocks, 256, 0, stream>>>(x, W0, as0, ad0, nullptr, hh, asb, adb, N);
    gat_csr2<<<gat_blocks, 256, 0, stream>>>(offs, csr_src, asb, adb, hh, b0, obuf, N, 1);
    // Layer 1: obuf -> obuf
    gemm_fused<128, 2, true><<<gemm_blocks, 256, 0, stream>>>(obuf, W1, as1, ad1, nullptr, hh, asb, adb, N);
    gat_csr2<<<gat_blocks, 256, 0, stream>>>(offs, csr_src, asb, adb, hh, b1, obuf, N, 1);
    // Layer 2: obuf -> d_out (heads=1, fp32 path, no relu)
    gemm_fused<64, 1, false><<<gemm_blocks, 256, 0, stream>>>(obuf, W2, as2, ad2, hbuf, nullptr, asb, adb, N);
    gat_csr1<<<gat_blocks, 256, 0, stream>>>(offs, csr_src, asb, adb, hbuf, b2, (float*)d_out, N, 0);
}

// Round 8
// 291.833 us; speedup vs baseline: 5.4823x; 1.0004x over previous
//
#include <hip/hip_runtime.h>
#include <hip/hip_fp16.h>

#define NEG_SLOPE 0.2f
#define EPSF 1e-16f

// ---------- GEMM + fused alpha epilogue ----------
template<int BN, int HEADS, bool OUTH>
__global__ __launch_bounds__(256) void gemm_fused(const float* __restrict__ X,
                                                  const float* __restrict__ W,
                                                  const float* __restrict__ asrc,
                                                  const float* __restrict__ adst,
                                                  float* __restrict__ OutF,
                                                  __half* __restrict__ OutH,
                                                  float* __restrict__ AS,
                                                  float* __restrict__ AD, int N) {
    constexpr int BM = 64, BK = 32, K = 128;
    constexpr int TN = BN / 16;  // 8 (BN=128) or 4 (BN=64)
    __shared__ float Xs[BM][BK + 4];
    __shared__ float Ws[BK][BN];
    const int tid = threadIdx.x;
    const int tx = tid & 15, ty = tid >> 4;
    const int row0 = blockIdx.x * BM;

    float acc[4][TN];
#pragma unroll
    for (int i = 0; i < 4; ++i)
#pragma unroll
        for (int j = 0; j < TN; ++j) acc[i][j] = 0.f;

    for (int kb = 0; kb < K; kb += BK) {
        __syncthreads();
        for (int idx = tid; idx < BK * (BN / 4); idx += 256) {
            int r = idx / (BN / 4), c4 = idx % (BN / 4);
            ((float4*)&Ws[r][0])[c4] = ((const float4*)&W[(size_t)(kb + r) * BN])[c4];
        }
        for (int t = tid; t < BM * (BK / 4); t += 256) {
            int r = t >> 3, c4 = t & 7;
            int gr = row0 + r;
            float4 v = make_float4(0.f, 0.f, 0.f, 0.f);
            if (gr < N) v = *((const float4*)&X[(size_t)gr * K + kb + c4 * 4]);
            Xs[r][c4 * 4 + 0] = v.x; Xs[r][c4 * 4 + 1] = v.y;
            Xs[r][c4 * 4 + 2] = v.z; Xs[r][c4 * 4 + 3] = v.w;
        }
        __syncthreads();
#pragma unroll
        for (int k = 0; k < BK; ++k) {
            float xr[4];
#pragma unroll
            for (int i = 0; i < 4; ++i) xr[i] = Xs[ty * 4 + i][k];
            float wv[TN];
#pragma unroll
            for (int j4 = 0; j4 < TN / 4; ++j4) {
                float4 w4 = ((float4*)&Ws[k][0])[tx * (TN / 4) + j4];
                wv[j4 * 4 + 0] = w4.x; wv[j4 * 4 + 1] = w4.y;
                wv[j4 * 4 + 2] = w4.z; wv[j4 * 4 + 3] = w4.w;
            }
#pragma unroll
            for (int i = 0; i < 4; ++i)
#pragma unroll
                for (int j = 0; j < TN; ++j) acc[i][j] = fmaf(xr[i], wv[j], acc[i][j]);
        }
    }

    float av[TN], dv[TN];
#pragma unroll
    for (int j = 0; j < TN; ++j) { av[j] = asrc[tx * TN + j]; dv[j] = adst[tx * TN + j]; }

#pragma unroll
    for (int i = 0; i < 4; ++i) {
        int gr = row0 + ty * 4 + i;
        if (gr >= N) continue;
        if (OUTH) {
            __half2 hp[TN / 2];
#pragma unroll
            for (int j2 = 0; j2 < TN / 2; ++j2)
                hp[j2] = __floats2half2_rn(acc[i][j2 * 2], acc[i][j2 * 2 + 1]);
            if (TN == 8)
                *((uint4*)&OutH[(size_t)gr * BN + tx * TN]) = *(uint4*)hp;
            else
                *((uint2*)&OutH[(size_t)gr * BN + tx * TN]) = *(uint2*)hp;
        } else {
#pragma unroll
            for (int j4 = 0; j4 < TN / 4; ++j4) {
                float4 o4 = make_float4(acc[i][j4 * 4 + 0], acc[i][j4 * 4 + 1],
                                        acc[i][j4 * 4 + 2], acc[i][j4 * 4 + 3]);
                *((float4*)&OutF[(size_t)gr * BN + tx * TN + j4 * 4]) = o4;
            }
        }
        float ps = 0.f, pd = 0.f;
#pragma unroll
        for (int j = 0; j < TN; ++j) { ps = fmaf(acc[i][j], av[j], ps); pd = fmaf(acc[i][j], dv[j], pd); }
        if (HEADS == 2) {
            for (int o = 1; o < 8; o <<= 1) { ps += __shfl_xor(ps, o, 64); pd += __shfl_xor(pd, o, 64); }
            if ((tx & 7) == 0) { AS[gr * 2 + (tx >> 3)] = ps; AD[gr * 2 + (tx >> 3)] = pd; }
        } else {
            for (int o = 1; o < 16; o <<= 1) { ps += __shfl_xor(ps, o, 64); pd += __shfl_xor(pd, o, 64); }
            if (tx == 0) { AS[gr] = ps; AD[gr] = pd; }
        }
    }
}

// ---------- CSR build ----------
__global__ void zero_kernel(int* __restrict__ p, int n4) {
    int i = blockIdx.x * blockDim.x + threadIdx.x;
    if (i < n4) ((int4*)p)[i] = make_int4(0, 0, 0, 0);
}

__global__ void hist_kernel(const int* __restrict__ ei, int E_raw, int N,
                            int* __restrict__ cnt) {
    const int E = E_raw + N;
    for (int e = blockIdx.x * blockDim.x + threadIdx.x; e < E; e += gridDim.x * blockDim.x) {
        int d = (e < E_raw) ? ei[E_raw + e] : e - E_raw;
        atomicAdd(&cnt[d], 1);
    }
}

__global__ __launch_bounds__(256) void scan_block(const int* __restrict__ cnt,
                                                  int* __restrict__ offs,
                                                  int* __restrict__ bsum, int N) {
    __shared__ int wsum[4];
    const int i = blockIdx.x * 256 + threadIdx.x;
    const int lane = threadIdx.x & 63, w = threadIdx.x >> 6;
    int v = (i < N) ? cnt[i] : 0;
    int incl = v;
    for (int o = 1; o < 64; o <<= 1) {
        int t = __shfl_up(incl, o, 64);
        if (lane >= o) incl += t;
    }
    if (lane == 63) wsum[w] = incl;
    __syncthreads();
    int prefix = 0;
    for (int k = 0; k < w; ++k) prefix += wsum[k];
    if (i < N) offs[i] = prefix + incl - v;
    if (threadIdx.x == 255) bsum[blockIdx.x] = prefix + incl;
}

__global__ __launch_bounds__(256) void scan_bsum(int* __restrict__ bsum, int nb) {
    __shared__ int wsum[4];
    const int lane = threadIdx.x & 63, w = threadIdx.x >> 6;
    int v = (threadIdx.x < nb) ? bsum[threadIdx.x] : 0;
    int incl = v;
    for (int o = 1; o < 64; o <<= 1) {
        int t = __shfl_up(incl, o, 64);
        if (lane >= o) incl += t;
    }
    if (lane == 63) wsum[w] = incl;
    __syncthreads();
    int prefix = 0;
    for (int k = 0; k < w; ++k) prefix += wsum[k];
    if (threadIdx.x < nb) bsum[threadIdx.x] = prefix + incl - v;
}

__global__ void scan_add(int* __restrict__ offs, const int* __restrict__ bsum,
                         int N, int E) {
    const int i = blockIdx.x * 256 + threadIdx.x;
    if (i < N) offs[i] += bsum[blockIdx.x];
    if (i == 0) offs[N] = E;
}

// XCD-partitioned scatter (see R5 notes). Position comes from counting cnt[d]
// down: pos = offs[d] + (--cnt[d]) -- fills each segment in reverse, no curs
// buffer / no D2D memcpy needed. cnt ends at 0 (re-zeroed next call anyway).
__global__ void scatter_edges_part(const int* __restrict__ ei, int E_raw, int N,
                                   int* __restrict__ cnt,
                                   const int* __restrict__ offs,
                                   int* __restrict__ csr_src) {
    const int NPART = 8;
    const int part = blockIdx.x & (NPART - 1);
    const int gblocks = gridDim.x >> 3;
    const int grank = blockIdx.x >> 3;
    const int tid = grank * blockDim.x + threadIdx.x;
    const int nthr = gblocks * blockDim.x;
    const int E = E_raw + N;
    const int dlo = (int)(((long long)N * part) / NPART);
    const int dhi = (int)(((long long)N * (part + 1)) / NPART);
    for (int e = tid; e < E; e += nthr) {
        int d = (e < E_raw) ? ei[E_raw + e] : e - E_raw;
        if (d >= dlo && d < dhi) {
            int s = (e < E_raw) ? ei[e] : d;
            int old = atomicSub(&cnt[d], 1);
            csr_src[offs[d] + old - 1] = s;
        }
    }
}

// ---------- fused GAT per-dst, heads=2, fp16 H ----------
__global__ __launch_bounds__(256) void gat_csr2(const int* __restrict__ offs,
                                                const int* __restrict__ csr_src,
                                                const float* __restrict__ AS,
                                                const float* __restrict__ AD,
                                                const __half* __restrict__ H,
                                                const float* __restrict__ bias,
                                                float* __restrict__ Out,
                                                int N, int do_relu) {
    __shared__ int   sS[4][64];
    __shared__ float sP0[4][64];
    __shared__ float sP1[4][64];
    const int lane = threadIdx.x & 63;
    const int w = threadIdx.x >> 6;
    const int wid = (int)((blockIdx.x * blockDim.x + threadIdx.x) >> 6);
    const int nw = (int)((gridDim.x * blockDim.x) >> 6);
    const int c = lane & 15;      // channels 8c..8c+7
    const int slot = lane >> 4;   // 4 edge slots
    const int myh = c >> 3;       // head owning my channels
    int* const sSw = &sS[w][0];
    const float* const myp = myh ? &sP1[w][0] : &sP0[w][0];
    const float4 bA = *(const float4*)&bias[8 * c];
    const float4 bB = *(const float4*)&bias[8 * c + 4];

    for (int n = wid; n < N; n += nw) {
        const int s0 = offs[n], s1 = offs[n + 1];
        const int deg = s1 - s0;
        const float2 adv = *(const float2*)&AD[(size_t)n * 2];
        float dn0 = 0.f, dn1 = 0.f, p0 = 0.f, p1 = 0.f;
        int sreg = 0;
        for (int i = s0 + lane; i < s1; i += 64) {
            int s = csr_src[i];
            float2 a2 = *(const float2*)&AS[(size_t)s * 2];
            float e0 = a2.x + adv.x, e1 = a2.y + adv.y;
            e0 = e0 > 0.f ? e0 : NEG_SLOPE * e0;
            e1 = e1 > 0.f ? e1 : NEG_SLOPE * e1;
            float pe0 = __expf(e0), pe1 = __expf(e1);
            dn0 += pe0; dn1 += pe1;
            if (i == s0 + lane) { sreg = s; p0 = pe0; p1 = pe1; }
        }
        for (int o = 1; o < 64; o <<= 1) {
            dn0 += __shfl_xor(dn0, o, 64);
            dn1 += __shfl_xor(dn1, o, 64);
        }
        const float myinv = 1.f / ((myh ? dn1 : dn0) + EPSF);

        float a[8];
#pragma unroll
        for (int j = 0; j < 8; ++j) a[j] = 0.f;
        if (deg <= 64) {
            sSw[lane] = sreg;
            sP0[w][lane] = p0;
            sP1[w][lane] = p1;
            const int npc = (deg + 3) >> 2;   // quads; phantom edges have p=0
            int t = 0;
            for (; t + 4 <= npc; t += 4) {
                int ss[4]; float pw[4]; uint4 hv[4];
#pragma unroll
                for (int k = 0; k < 4; ++k) {
                    int idx = 4 * (t + k) + slot;
                    ss[k] = sSw[idx];
                    pw[k] = myp[idx];
                }
#pragma unroll
                for (int k = 0; k < 4; ++k)
                    hv[k] = *(const uint4*)&H[(size_t)ss[k] * 128 + 8 * c];
#pragma unroll
                for (int k = 0; k < 4; ++k) {
                    const __half2* h2 = (const __half2*)&hv[k];
#pragma unroll
                    for (int j = 0; j < 4; ++j) {
                        float2 f = __half22float2(h2[j]);
                        a[2 * j]     = fmaf(f.x, pw[k], a[2 * j]);
                        a[2 * j + 1] = fmaf(f.y, pw[k], a[2 * j + 1]);
                    }
                }
            }
            for (; t < npc; ++t) {
                int idx = 4 * t + slot;
                int s = sSw[idx];
                float pw = myp[idx];
                uint4 hv = *(const uint4*)&H[(size_t)s * 128 + 8 * c];
                const __half2* h2 = (const __half2*)&hv;
#pragma unroll
                for (int j = 0; j < 4; ++j) {
                    float2 f = __half22float2(h2[j]);
                    a[2 * j]     = fmaf(f.x, pw, a[2 * j]);
                    a[2 * j + 1] = fmaf(f.y, pw, a[2 * j + 1]);
                }
            }
        } else {
            const float advh = myh ? adv.y : adv.x;
            for (int i = s0 + slot; i < s1; i += 4) {
                int s = csr_src[i];
                float e = AS[(size_t)s * 2 + myh] + advh;
                e = e > 0.f ? e : NEG_SLOPE * e;
                float pw = __expf(e);
                uint4 hv = *(const uint4*)&H[(size_t)s * 128 + 8 * c];
                const __half2* h2 = (const __half2*)&hv;
#pragma unroll
                for (int j = 0; j < 4; ++j) {
                    float2 f = __half22float2(h2[j]);
                    a[2 * j]     = fmaf(f.x, pw, a[2 * j]);
                    a[2 * j + 1] = fmaf(f.y, pw, a[2 * j + 1]);
                }
            }
        }
#pragma unroll
        for (int j = 0; j < 8; ++j) {
            a[j] += __shfl_xor(a[j], 16, 64);
            a[j] += __shfl_xor(a[j], 32, 64);
        }
        if (lane < 16) {
            float4 oA, oB;
            oA.x = a[0] * myinv + bA.x; oA.y = a[1] * myinv + bA.y;
            oA.z = a[2] * myinv + bA.z; oA.w = a[3] * myinv + bA.w;
            oB.x = a[4] * myinv + bB.x; oB.y = a[5] * myinv + bB.y;
            oB.z = a[6] * myinv + bB.z; oB.w = a[7] * myinv + bB.w;
            if (do_relu) {
                oA.x = fmaxf(oA.x, 0.f); oA.y = fmaxf(oA.y, 0.f);
                oA.z = fmaxf(oA.z, 0.f); oA.w = fmaxf(oA.w, 0.f);
                oB.x = fmaxf(oB.x, 0.f); oB.y = fmaxf(oB.y, 0.f);
                oB.z = fmaxf(oB.z, 0.f); oB.w = fmaxf(oB.w, 0.f);
            }
            *(float4*)&Out[(size_t)n * 128 + 8 * c] = oA;
            *(float4*)&Out[(size_t)n * 128 + 8 * c + 4] = oB;
        }
    }
}

// ---------- fused GAT per-dst, heads=1, fp32 H (final layer) ----------
__global__ __launch_bounds__(256) void gat_csr1(const int* __restrict__ offs,
                                                const int* __restrict__ csr_src,
                                                const float* __restrict__ AS,
                                                const float* __restrict__ AD,
                                                const float* __restrict__ H,
                                                const float* __restrict__ bias,
                                                float* __restrict__ Out,
                                                int N, int do_relu) {
    __shared__ int   sS[4][64];
    __shared__ float sP[4][64];
    const int lane = threadIdx.x & 63;
    const int w = threadIdx.x >> 6;
    const int wid = (int)((blockIdx.x * blockDim.x + threadIdx.x) >> 6);
    const int nw = (int)((gridDim.x * blockDim.x) >> 6);
    const int c = lane & 15;     // channels 4c..4c+3
    const int slot = lane >> 4;  // 4 edge slots
    int* const sSw = &sS[w][0];
    float* const sPw = &sP[w][0];
    const float4 b4 = *(const float4*)&bias[4 * c];

    for (int n = wid; n < N; n += nw) {
        const int s0 = offs[n], s1 = offs[n + 1];
        const int deg = s1 - s0;
        const float adv0 = AD[n];
        float dn0 = 0.f, p0 = 0.f;
        int sreg = 0;
        for (int i = s0 + lane; i < s1; i += 64) {
            int s = csr_src[i];
            float e0 = AS[s] + adv0;
            e0 = e0 > 0.f ? e0 : NEG_SLOPE * e0;
            float pe0 = __expf(e0);
            dn0 += pe0;
            if (i == s0 + lane) { sreg = s; p0 = pe0; }
        }
        for (int o = 1; o < 64; o <<= 1) dn0 += __shfl_xor(dn0, o, 64);
        const float inv0 = 1.f / (dn0 + EPSF);

        float a[4];
#pragma unroll
        for (int j = 0; j < 4; ++j) a[j] = 0.f;
        if (deg <= 64) {
            sSw[lane] = sreg;
            sPw[lane] = p0;
            const int npc = (deg + 3) >> 2;
            int t = 0;
            for (; t + 4 <= npc; t += 4) {
                int ss[4]; float pw[4]; float4 hv[4];
#pragma unroll
                for (int k = 0; k < 4; ++k) {
                    int idx = 4 * (t + k) + slot;
                    ss[k] = sSw[idx];
                    pw[k] = sPw[idx];
                }
#pragma unroll
                for (int k = 0; k < 4; ++k)
                    hv[k] = *(const float4*)&H[(size_t)ss[k] * 64 + 4 * c];
#pragma unroll
                for (int k = 0; k < 4; ++k) {
                    a[0] = fmaf(hv[k].x, pw[k], a[0]);
                    a[1] = fmaf(hv[k].y, pw[k], a[1]);
                    a[2] = fmaf(hv[k].z, pw[k], a[2]);
                    a[3] = fmaf(hv[k].w, pw[k], a[3]);
                }
            }
            for (; t < npc; ++t) {
                int idx = 4 * t + slot;
                int s = sSw[idx];
                float pw = sPw[idx];
                float4 hv = *(const float4*)&H[(size_t)s * 64 + 4 * c];
                a[0] = fmaf(hv.x, pw, a[0]);
                a[1] = fmaf(hv.y, pw, a[1]);
                a[2] = fmaf(hv.z, pw, a[2]);
                a[3] = fmaf(hv.w, pw, a[3]);
            }
        } else {
            for (int i = s0 + slot; i < s1; i += 4) {
                int s = csr_src[i];
                float e = AS[s] + adv0;
                e = e > 0.f ? e : NEG_SLOPE * e;
                float pw = __expf(e);
                float4 hv = *(const float4*)&H[(size_t)s * 64 + 4 * c];
                a[0] = fmaf(hv.x, pw, a[0]);
                a[1] = fmaf(hv.y, pw, a[1]);
                a[2] = fmaf(hv.z, pw, a[2]);
                a[3] = fmaf(hv.w, pw, a[3]);
            }
        }
#pragma unroll
        for (int j = 0; j < 4; ++j) {
            a[j] += __shfl_xor(a[j], 16, 64);
            a[j] += __shfl_xor(a[j], 32, 64);
        }
        if (lane < 16) {
            float4 o;
            o.x = a[0] * inv0 + b4.x;
            o.y = a[1] * inv0 + b4.y;
            o.z = a[2] * inv0 + b4.z;
            o.w = a[3] * inv0 + b4.w;
            if (do_relu) {
                o.x = fmaxf(o.x, 0.f); o.y = fmaxf(o.y, 0.f);
                o.z = fmaxf(o.z, 0.f); o.w = fmaxf(o.w, 0.f);
            }
            *(float4*)&Out[(size_t)n * 64 + 4 * c] = o;
        }
    }
}

extern "C" void kernel_launch(void* const* d_in, const int* in_sizes, int n_in,
                              void* d_out, int out_size, void* d_ws, size_t ws_size,
                              hipStream_t stream) {
    const float* x   = (const float*)d_in[0];
    const int*   ei  = (const int*)d_in[1];
    const float* W0  = (const float*)d_in[2];
    const float* as0 = (const float*)d_in[3];
    const float* ad0 = (const float*)d_in[4];
    const float* b0  = (const float*)d_in[5];
    const float* W1  = (const float*)d_in[6];
    const float* as1 = (const float*)d_in[7];
    const float* ad1 = (const float*)d_in[8];
    const float* b1  = (const float*)d_in[9];
    const float* W2  = (const float*)d_in[10];
    const float* as2 = (const float*)d_in[11];
    const float* ad2 = (const float*)d_in[12];
    const float* b2  = (const float*)d_in[13];

    const int N = in_sizes[0] / 128;
    const int E_raw = in_sizes[1] / 2;
    const int E = E_raw + N;

    char* ws = (char*)d_ws;
    size_t off = 0;
    auto alloc = [&](size_t bytes) {
        void* p = ws + off;
        off = (off + bytes + 255) & ~(size_t)255;
        return p;
    };
    float* hbuf = (float*)alloc((size_t)N * 128 * 4);
    float* obuf = (float*)alloc((size_t)N * 128 * 4);
    float* asb  = (float*)alloc((size_t)N * 2 * 4);
    float* adb  = (float*)alloc((size_t)N * 2 * 4);
    int*   cnt  = (int*)alloc((size_t)(N + 4) * 4);
    int*   offs = (int*)alloc((size_t)(N + 1) * 4);
    int*   bsum = (int*)alloc(1024);
    int* csr_src = (int*)alloc((size_t)E * 4);
    __half* hh = (__half*)hbuf;
    (void)ws_size; (void)n_in; (void)out_size;

    // ---- build CSR grouped by dst (reused by all 3 layers) ----
    const int nb = (N + 255) / 256;
    const int n4 = (N + 3) / 4;
    zero_kernel<<<(n4 + 255) / 256, 256, 0, stream>>>(cnt, n4);
    hist_kernel<<<2048, 256, 0, stream>>>(ei, E_raw, N, cnt);
    scan_block<<<nb, 256, 0, stream>>>(cnt, offs, bsum, N);
    scan_bsum<<<1, 256, 0, stream>>>(bsum, nb);
    scan_add<<<nb, 256, 0, stream>>>(offs, bsum, N, E);
    scatter_edges_part<<<2048, 256, 0, stream>>>(ei, E_raw, N, cnt, offs, csr_src);

    const int gemm_blocks = (N + 63) / 64;
    const int gat_blocks = (N * 64 + 255) / 256;

    // Layer 0: x -> obuf (relu)
    gemm_fused<128, 2, true><<<gemm_blocks, 256, 0, stream>>>(x, W0, as0, ad0, nullptr, hh, asb, adb, N);
    gat_csr2<<<gat_blocks, 256, 0, stream>>>(offs, csr_src, asb, adb, hh, b0, obuf, N, 1);
    // Layer 1: obuf -> obuf
    gemm_fused<128, 2, true><<<gemm_blocks, 256, 0, stream>>>(obuf, W1, as1, ad1, nullptr, hh, asb, adb, N);
    gat_csr2<<<gat_blocks, 256, 0, stream>>>(offs, csr_src, asb, adb, hh, b1, obuf, N, 1);
    // Layer 2: obuf -> d_out (heads=1, fp32 path, no relu)
    gemm_fused<64, 1, false><<<gemm_blocks, 256, 0, stream>>>(obuf, W2, as2, ad2, hbuf, nullptr, asb, adb, N);
    gat_csr1<<<gat_blocks, 256, 0, stream>>>(offs, csr_src, asb, adb, hbuf, b2, (float*)d_out, N, 0);
}

// Round 9
// 277.710 us; speedup vs baseline: 5.7611x; 1.0509x over previous
//
#include <hip/hip_runtime.h>
#include <hip/hip_fp16.h>

#define NEG_SLOPE 0.2f
#define EPSF 1e-16f

// ---------- GEMM + fused alpha epilogue ----------
// XT: input activation type (float or __half). Inner math stays fp32.
template<int BN, int HEADS, bool OUTH, typename XT>
__global__ __launch_bounds__(256) void gemm_fused(const XT* __restrict__ X,
                                                  const float* __restrict__ W,
                                                  const float* __restrict__ asrc,
                                                  const float* __restrict__ adst,
                                                  float* __restrict__ OutF,
                                                  __half* __restrict__ OutH,
                                                  float* __restrict__ AS,
                                                  float* __restrict__ AD, int N) {
    constexpr int BM = 64, BK = 32, K = 128;
    constexpr int TN = BN / 16;  // 8 (BN=128) or 4 (BN=64)
    __shared__ float Xs[BM][BK + 4];
    __shared__ float Ws[BK][BN];
    const int tid = threadIdx.x;
    const int tx = tid & 15, ty = tid >> 4;
    const int row0 = blockIdx.x * BM;

    float acc[4][TN];
#pragma unroll
    for (int i = 0; i < 4; ++i)
#pragma unroll
        for (int j = 0; j < TN; ++j) acc[i][j] = 0.f;

    for (int kb = 0; kb < K; kb += BK) {
        __syncthreads();
        for (int idx = tid; idx < BK * (BN / 4); idx += 256) {
            int r = idx / (BN / 4), c4 = idx % (BN / 4);
            ((float4*)&Ws[r][0])[c4] = ((const float4*)&W[(size_t)(kb + r) * BN])[c4];
        }
        for (int t = tid; t < BM * (BK / 4); t += 256) {
            int r = t >> 3, c4 = t & 7;
            int gr = row0 + r;
            float f[4] = {0.f, 0.f, 0.f, 0.f};
            if (gr < N) {
                if constexpr (sizeof(XT) == 2) {
                    uint2 raw = *((const uint2*)&X[(size_t)gr * K + kb + c4 * 4]);
                    const __half2* hp = (const __half2*)&raw;
                    float2 f0 = __half22float2(hp[0]);
                    float2 f1 = __half22float2(hp[1]);
                    f[0] = f0.x; f[1] = f0.y; f[2] = f1.x; f[3] = f1.y;
                } else {
                    float4 v = *((const float4*)&X[(size_t)gr * K + kb + c4 * 4]);
                    f[0] = v.x; f[1] = v.y; f[2] = v.z; f[3] = v.w;
                }
            }
            Xs[r][c4 * 4 + 0] = f[0]; Xs[r][c4 * 4 + 1] = f[1];
            Xs[r][c4 * 4 + 2] = f[2]; Xs[r][c4 * 4 + 3] = f[3];
        }
        __syncthreads();
#pragma unroll
        for (int k = 0; k < BK; ++k) {
            float xr[4];
#pragma unroll
            for (int i = 0; i < 4; ++i) xr[i] = Xs[ty * 4 + i][k];
            float wv[TN];
#pragma unroll
            for (int j4 = 0; j4 < TN / 4; ++j4) {
                float4 w4 = ((float4*)&Ws[k][0])[tx * (TN / 4) + j4];
                wv[j4 * 4 + 0] = w4.x; wv[j4 * 4 + 1] = w4.y;
                wv[j4 * 4 + 2] = w4.z; wv[j4 * 4 + 3] = w4.w;
            }
#pragma unroll
            for (int i = 0; i < 4; ++i)
#pragma unroll
                for (int j = 0; j < TN; ++j) acc[i][j] = fmaf(xr[i], wv[j], acc[i][j]);
        }
    }

    float av[TN], dv[TN];
#pragma unroll
    for (int j = 0; j < TN; ++j) { av[j] = asrc[tx * TN + j]; dv[j] = adst[tx * TN + j]; }

#pragma unroll
    for (int i = 0; i < 4; ++i) {
        int gr = row0 + ty * 4 + i;
        if (gr >= N) continue;
        if (OUTH) {
            __half2 hp[TN / 2];
#pragma unroll
            for (int j2 = 0; j2 < TN / 2; ++j2)
                hp[j2] = __floats2half2_rn(acc[i][j2 * 2], acc[i][j2 * 2 + 1]);
            if (TN == 8)
                *((uint4*)&OutH[(size_t)gr * BN + tx * TN]) = *(uint4*)hp;
            else
                *((uint2*)&OutH[(size_t)gr * BN + tx * TN]) = *(uint2*)hp;
        } else {
#pragma unroll
            for (int j4 = 0; j4 < TN / 4; ++j4) {
                float4 o4 = make_float4(acc[i][j4 * 4 + 0], acc[i][j4 * 4 + 1],
                                        acc[i][j4 * 4 + 2], acc[i][j4 * 4 + 3]);
                *((float4*)&OutF[(size_t)gr * BN + tx * TN + j4 * 4]) = o4;
            }
        }
        float ps = 0.f, pd = 0.f;
#pragma unroll
        for (int j = 0; j < TN; ++j) { ps = fmaf(acc[i][j], av[j], ps); pd = fmaf(acc[i][j], dv[j], pd); }
        if (HEADS == 2) {
            for (int o = 1; o < 8; o <<= 1) { ps += __shfl_xor(ps, o, 64); pd += __shfl_xor(pd, o, 64); }
            if ((tx & 7) == 0) { AS[gr * 2 + (tx >> 3)] = ps; AD[gr * 2 + (tx >> 3)] = pd; }
        } else {
            for (int o = 1; o < 16; o <<= 1) { ps += __shfl_xor(ps, o, 64); pd += __shfl_xor(pd, o, 64); }
            if (tx == 0) { AS[gr] = ps; AD[gr] = pd; }
        }
    }
}

// ---------- CSR build ----------
__global__ void zero_kernel(int* __restrict__ p, int n4) {
    int i = blockIdx.x * blockDim.x + threadIdx.x;
    if (i < n4) ((int4*)p)[i] = make_int4(0, 0, 0, 0);
}

__global__ void hist_kernel(const int* __restrict__ ei, int E_raw, int N,
                            int* __restrict__ cnt) {
    const int E = E_raw + N;
    for (int e = blockIdx.x * blockDim.x + threadIdx.x; e < E; e += gridDim.x * blockDim.x) {
        int d = (e < E_raw) ? ei[E_raw + e] : e - E_raw;
        atomicAdd(&cnt[d], 1);
    }
}

__global__ __launch_bounds__(256) void scan_block(const int* __restrict__ cnt,
                                                  int* __restrict__ offs,
                                                  int* __restrict__ bsum, int N) {
    __shared__ int wsum[4];
    const int i = blockIdx.x * 256 + threadIdx.x;
    const int lane = threadIdx.x & 63, w = threadIdx.x >> 6;
    int v = (i < N) ? cnt[i] : 0;
    int incl = v;
    for (int o = 1; o < 64; o <<= 1) {
        int t = __shfl_up(incl, o, 64);
        if (lane >= o) incl += t;
    }
    if (lane == 63) wsum[w] = incl;
    __syncthreads();
    int prefix = 0;
    for (int k = 0; k < w; ++k) prefix += wsum[k];
    if (i < N) offs[i] = prefix + incl - v;
    if (threadIdx.x == 255) bsum[blockIdx.x] = prefix + incl;
}

__global__ __launch_bounds__(256) void scan_bsum(int* __restrict__ bsum, int nb) {
    __shared__ int wsum[4];
    const int lane = threadIdx.x & 63, w = threadIdx.x >> 6;
    int v = (threadIdx.x < nb) ? bsum[threadIdx.x] : 0;
    int incl = v;
    for (int o = 1; o < 64; o <<= 1) {
        int t = __shfl_up(incl, o, 64);
        if (lane >= o) incl += t;
    }
    if (lane == 63) wsum[w] = incl;
    __syncthreads();
    int prefix = 0;
    for (int k = 0; k < w; ++k) prefix += wsum[k];
    if (threadIdx.x < nb) bsum[threadIdx.x] = prefix + incl - v;
}

__global__ void scan_add(int* __restrict__ offs, const int* __restrict__ bsum,
                         int N, int E) {
    const int i = blockIdx.x * 256 + threadIdx.x;
    if (i < N) offs[i] += bsum[blockIdx.x];
    if (i == 0) offs[N] = E;
}

// XCD-partitioned scatter (R5). pos = offs[d] + (--cnt[d]); cnt ends at 0.
__global__ void scatter_edges_part(const int* __restrict__ ei, int E_raw, int N,
                                   int* __restrict__ cnt,
                                   const int* __restrict__ offs,
                                   int* __restrict__ csr_src) {
    const int NPART = 8;
    const int part = blockIdx.x & (NPART - 1);
    const int gblocks = gridDim.x >> 3;
    const int grank = blockIdx.x >> 3;
    const int tid = grank * blockDim.x + threadIdx.x;
    const int nthr = gblocks * blockDim.x;
    const int E = E_raw + N;
    const int dlo = (int)(((long long)N * part) / NPART);
    const int dhi = (int)(((long long)N * (part + 1)) / NPART);
    for (int e = tid; e < E; e += nthr) {
        int d = (e < E_raw) ? ei[E_raw + e] : e - E_raw;
        if (d >= dlo && d < dhi) {
            int s = (e < E_raw) ? ei[e] : d;
            int old = atomicSub(&cnt[d], 1);
            csr_src[offs[d] + old - 1] = s;
        }
    }
}

// ---------- fused GAT per-dst, heads=2, fp16 H, fp16 out ----------
__global__ __launch_bounds__(256) void gat_csr2(const int* __restrict__ offs,
                                                const int* __restrict__ csr_src,
                                                const float* __restrict__ AS,
                                                const float* __restrict__ AD,
                                                const __half* __restrict__ H,
                                                const float* __restrict__ bias,
                                                __half* __restrict__ Out,
                                                int N, int do_relu) {
    __shared__ int   sS[4][64];
    __shared__ float sP0[4][64];
    __shared__ float sP1[4][64];
    const int lane = threadIdx.x & 63;
    const int w = threadIdx.x >> 6;
    const int wid = (int)((blockIdx.x * blockDim.x + threadIdx.x) >> 6);
    const int nw = (int)((gridDim.x * blockDim.x) >> 6);
    const int c = lane & 15;      // channels 8c..8c+7
    const int slot = lane >> 4;   // 4 edge slots
    const int myh = c >> 3;       // head owning my channels
    int* const sSw = &sS[w][0];
    const float* const myp = myh ? &sP1[w][0] : &sP0[w][0];
    const float4 bA = *(const float4*)&bias[8 * c];
    const float4 bB = *(const float4*)&bias[8 * c + 4];

    for (int n = wid; n < N; n += nw) {
        const int s0 = offs[n], s1 = offs[n + 1];
        const int deg = s1 - s0;
        const float2 adv = *(const float2*)&AD[(size_t)n * 2];
        float dn0 = 0.f, dn1 = 0.f, p0 = 0.f, p1 = 0.f;
        int sreg = 0;
        for (int i = s0 + lane; i < s1; i += 64) {
            int s = csr_src[i];
            float2 a2 = *(const float2*)&AS[(size_t)s * 2];
            float e0 = a2.x + adv.x, e1 = a2.y + adv.y;
            e0 = e0 > 0.f ? e0 : NEG_SLOPE * e0;
            e1 = e1 > 0.f ? e1 : NEG_SLOPE * e1;
            float pe0 = __expf(e0), pe1 = __expf(e1);
            dn0 += pe0; dn1 += pe1;
            if (i == s0 + lane) { sreg = s; p0 = pe0; p1 = pe1; }
        }
        for (int o = 1; o < 64; o <<= 1) {
            dn0 += __shfl_xor(dn0, o, 64);
            dn1 += __shfl_xor(dn1, o, 64);
        }
        const float myinv = 1.f / ((myh ? dn1 : dn0) + EPSF);

        float a[8];
#pragma unroll
        for (int j = 0; j < 8; ++j) a[j] = 0.f;
        if (deg <= 64) {
            sSw[lane] = sreg;
            sP0[w][lane] = p0;
            sP1[w][lane] = p1;
            const int npc = (deg + 3) >> 2;   // quads; phantom edges have p=0
            int t = 0;
            for (; t + 4 <= npc; t += 4) {
                int ss[4]; float pw[4]; uint4 hv[4];
#pragma unroll
                for (int k = 0; k < 4; ++k) {
                    int idx = 4 * (t + k) + slot;
                    ss[k] = sSw[idx];
                    pw[k] = myp[idx];
                }
#pragma unroll
                for (int k = 0; k < 4; ++k)
                    hv[k] = *(const uint4*)&H[(size_t)ss[k] * 128 + 8 * c];
#pragma unroll
                for (int k = 0; k < 4; ++k) {
                    const __half2* h2 = (const __half2*)&hv[k];
#pragma unroll
                    for (int j = 0; j < 4; ++j) {
                        float2 f = __half22float2(h2[j]);
                        a[2 * j]     = fmaf(f.x, pw[k], a[2 * j]);
                        a[2 * j + 1] = fmaf(f.y, pw[k], a[2 * j + 1]);
                    }
                }
            }
            for (; t < npc; ++t) {
                int idx = 4 * t + slot;
                int s = sSw[idx];
                float pw = myp[idx];
                uint4 hv = *(const uint4*)&H[(size_t)s * 128 + 8 * c];
                const __half2* h2 = (const __half2*)&hv;
#pragma unroll
                for (int j = 0; j < 4; ++j) {
                    float2 f = __half22float2(h2[j]);
                    a[2 * j]     = fmaf(f.x, pw, a[2 * j]);
                    a[2 * j + 1] = fmaf(f.y, pw, a[2 * j + 1]);
                }
            }
        } else {
            const float advh = myh ? adv.y : adv.x;
            for (int i = s0 + slot; i < s1; i += 4) {
                int s = csr_src[i];
                float e = AS[(size_t)s * 2 + myh] + advh;
                e = e > 0.f ? e : NEG_SLOPE * e;
                float pw = __expf(e);
                uint4 hv = *(const uint4*)&H[(size_t)s * 128 + 8 * c];
                const __half2* h2 = (const __half2*)&hv;
#pragma unroll
                for (int j = 0; j < 4; ++j) {
                    float2 f = __half22float2(h2[j]);
                    a[2 * j]     = fmaf(f.x, pw, a[2 * j]);
                    a[2 * j + 1] = fmaf(f.y, pw, a[2 * j + 1]);
                }
            }
        }
#pragma unroll
        for (int j = 0; j < 8; ++j) {
            a[j] += __shfl_xor(a[j], 16, 64);
            a[j] += __shfl_xor(a[j], 32, 64);
        }
        if (lane < 16) {
            float o[8];
            o[0] = a[0] * myinv + bA.x; o[1] = a[1] * myinv + bA.y;
            o[2] = a[2] * myinv + bA.z; o[3] = a[3] * myinv + bA.w;
            o[4] = a[4] * myinv + bB.x; o[5] = a[5] * myinv + bB.y;
            o[6] = a[6] * myinv + bB.z; o[7] = a[7] * myinv + bB.w;
            if (do_relu) {
#pragma unroll
                for (int j = 0; j < 8; ++j) o[j] = fmaxf(o[j], 0.f);
            }
            __half2 hp[4];
#pragma unroll
            for (int j = 0; j < 4; ++j) hp[j] = __floats2half2_rn(o[2 * j], o[2 * j + 1]);
            *(uint4*)&Out[(size_t)n * 128 + 8 * c] = *(uint4*)hp;
        }
    }
}

// ---------- fused GAT per-dst, heads=1, fp16 H, fp32 out (final layer) ----------
__global__ __launch_bounds__(256) void gat_csr1(const int* __restrict__ offs,
                                                const int* __restrict__ csr_src,
                                                const float* __restrict__ AS,
                                                const float* __restrict__ AD,
                                                const __half* __restrict__ H,
                                                const float* __restrict__ bias,
                                                float* __restrict__ Out,
                                                int N, int do_relu) {
    __shared__ int   sS[4][64];
    __shared__ float sP[4][64];
    const int lane = threadIdx.x & 63;
    const int w = threadIdx.x >> 6;
    const int wid = (int)((blockIdx.x * blockDim.x + threadIdx.x) >> 6);
    const int nw = (int)((gridDim.x * blockDim.x) >> 6);
    const int c = lane & 15;     // channels 4c..4c+3
    const int slot = lane >> 4;  // 4 edge slots
    int* const sSw = &sS[w][0];
    float* const sPw = &sP[w][0];
    const float4 b4 = *(const float4*)&bias[4 * c];

    for (int n = wid; n < N; n += nw) {
        const int s0 = offs[n], s1 = offs[n + 1];
        const int deg = s1 - s0;
        const float adv0 = AD[n];
        float dn0 = 0.f, p0 = 0.f;
        int sreg = 0;
        for (int i = s0 + lane; i < s1; i += 64) {
            int s = csr_src[i];
            float e0 = AS[s] + adv0;
            e0 = e0 > 0.f ? e0 : NEG_SLOPE * e0;
            float pe0 = __expf(e0);
            dn0 += pe0;
            if (i == s0 + lane) { sreg = s; p0 = pe0; }
        }
        for (int o = 1; o < 64; o <<= 1) dn0 += __shfl_xor(dn0, o, 64);
        const float inv0 = 1.f / (dn0 + EPSF);

        float a[4];
#pragma unroll
        for (int j = 0; j < 4; ++j) a[j] = 0.f;
        if (deg <= 64) {
            sSw[lane] = sreg;
            sPw[lane] = p0;
            const int npc = (deg + 3) >> 2;
            int t = 0;
            for (; t + 4 <= npc; t += 4) {
                int ss[4]; float pw[4]; uint2 hv[4];
#pragma unroll
                for (int k = 0; k < 4; ++k) {
                    int idx = 4 * (t + k) + slot;
                    ss[k] = sSw[idx];
                    pw[k] = sPw[idx];
                }
#pragma unroll
                for (int k = 0; k < 4; ++k)
                    hv[k] = *(const uint2*)&H[(size_t)ss[k] * 64 + 4 * c];
#pragma unroll
                for (int k = 0; k < 4; ++k) {
                    const __half2* h2 = (const __half2*)&hv[k];
                    float2 f01 = __half22float2(h2[0]);
                    float2 f23 = __half22float2(h2[1]);
                    a[0] = fmaf(f01.x, pw[k], a[0]);
                    a[1] = fmaf(f01.y, pw[k], a[1]);
                    a[2] = fmaf(f23.x, pw[k], a[2]);
                    a[3] = fmaf(f23.y, pw[k], a[3]);
                }
            }
            for (; t < npc; ++t) {
                int idx = 4 * t + slot;
                int s = sSw[idx];
                float pw = sPw[idx];
                uint2 hv = *(const uint2*)&H[(size_t)s * 64 + 4 * c];
                const __half2* h2 = (const __half2*)&hv;
                float2 f01 = __half22float2(h2[0]);
                float2 f23 = __half22float2(h2[1]);
                a[0] = fmaf(f01.x, pw, a[0]);
                a[1] = fmaf(f01.y, pw, a[1]);
                a[2] = fmaf(f23.x, pw, a[2]);
                a[3] = fmaf(f23.y, pw, a[3]);
            }
        } else {
            for (int i = s0 + slot; i < s1; i += 4) {
                int s = csr_src[i];
                float e = AS[s] + adv0;
                e = e > 0.f ? e : NEG_SLOPE * e;
                float pw = __expf(e);
                uint2 hv = *(const uint2*)&H[(size_t)s * 64 + 4 * c];
                const __half2* h2 = (const __half2*)&hv;
                float2 f01 = __half22float2(h2[0]);
                float2 f23 = __half22float2(h2[1]);
                a[0] = fmaf(f01.x, pw, a[0]);
                a[1] = fmaf(f01.y, pw, a[1]);
                a[2] = fmaf(f23.x, pw, a[2]);
                a[3] = fmaf(f23.y, pw, a[3]);
            }
        }
#pragma unroll
        for (int j = 0; j < 4; ++j) {
            a[j] += __shfl_xor(a[j], 16, 64);
            a[j] += __shfl_xor(a[j], 32, 64);
        }
        if (lane < 16) {
            float4 o;
            o.x = a[0] * inv0 + b4.x;
            o.y = a[1] * inv0 + b4.y;
            o.z = a[2] * inv0 + b4.z;
            o.w = a[3] * inv0 + b4.w;
            if (do_relu) {
                o.x = fmaxf(o.x, 0.f); o.y = fmaxf(o.y, 0.f);
                o.z = fmaxf(o.z, 0.f); o.w = fmaxf(o.w, 0.f);
            }
            *(float4*)&Out[(size_t)n * 64 + 4 * c] = o;
        }
    }
}

extern "C" void kernel_launch(void* const* d_in, const int* in_sizes, int n_in,
                              void* d_out, int out_size, void* d_ws, size_t ws_size,
                              hipStream_t stream) {
    const float* x   = (const float*)d_in[0];
    const int*   ei  = (const int*)d_in[1];
    const float* W0  = (const float*)d_in[2];
    const float* as0 = (const float*)d_in[3];
    const float* ad0 = (const float*)d_in[4];
    const float* b0  = (const float*)d_in[5];
    const float* W1  = (const float*)d_in[6];
    const float* as1 = (const float*)d_in[7];
    const float* ad1 = (const float*)d_in[8];
    const float* b1  = (const float*)d_in[9];
    const float* W2  = (const float*)d_in[10];
    const float* as2 = (const float*)d_in[11];
    const float* ad2 = (const float*)d_in[12];
    const float* b2  = (const float*)d_in[13];

    const int N = in_sizes[0] / 128;
    const int E_raw = in_sizes[1] / 2;
    const int E = E_raw + N;

    char* ws = (char*)d_ws;
    size_t off = 0;
    auto alloc = [&](size_t bytes) {
        void* p = ws + off;
        off = (off + bytes + 255) & ~(size_t)255;
        return p;
    };
    __half* hh    = (__half*)alloc((size_t)N * 128 * 2);  // h (fp16, all layers)
    __half* obufh = (__half*)alloc((size_t)N * 128 * 2);  // inter-layer activations fp16
    float* asb  = (float*)alloc((size_t)N * 2 * 4);
    float* adb  = (float*)alloc((size_t)N * 2 * 4);
    int*   cnt  = (int*)alloc((size_t)(N + 4) * 4);
    int*   offs = (int*)alloc((size_t)(N + 1) * 4);
    int*   bsum = (int*)alloc(1024);
    int* csr_src = (int*)alloc((size_t)E * 4);
    (void)ws_size; (void)n_in; (void)out_size;

    // ---- build CSR grouped by dst (reused by all 3 layers) ----
    const int nb = (N + 255) / 256;
    const int n4 = (N + 3) / 4;
    zero_kernel<<<(n4 + 255) / 256, 256, 0, stream>>>(cnt, n4);
    hist_kernel<<<2048, 256, 0, stream>>>(ei, E_raw, N, cnt);
    scan_block<<<nb, 256, 0, stream>>>(cnt, offs, bsum, N);
    scan_bsum<<<1, 256, 0, stream>>>(bsum, nb);
    scan_add<<<nb, 256, 0, stream>>>(offs, bsum, N, E);
    scatter_edges_part<<<2048, 256, 0, stream>>>(ei, E_raw, N, cnt, offs, csr_src);

    const int gemm_blocks = (N + 63) / 64;
    const int gat_blocks = (N * 64 + 255) / 256;

    // Layer 0: x (fp32) -> obufh (fp16, relu)
    gemm_fused<128, 2, true, float><<<gemm_blocks, 256, 0, stream>>>(x, W0, as0, ad0, nullptr, hh, asb, adb, N);
    gat_csr2<<<gat_blocks, 256, 0, stream>>>(offs, csr_src, asb, adb, hh, b0, obufh, N, 1);
    // Layer 1: obufh (fp16) -> obufh (fp16, relu)
    gemm_fused<128, 2, true, __half><<<gemm_blocks, 256, 0, stream>>>(obufh, W1, as1, ad1, nullptr, hh, asb, adb, N);
    gat_csr2<<<gat_blocks, 256, 0, stream>>>(offs, csr_src, asb, adb, hh, b1, obufh, N, 1);
    // Layer 2: obufh (fp16) -> d_out (fp32, heads=1, no relu); h stored fp16
    gemm_fused<64, 1, true, __half><<<gemm_blocks, 256, 0, stream>>>(obufh, W2, as2, ad2, nullptr, hh, asb, adb, N);
    gat_csr1<<<gat_blocks, 256, 0, stream>>>(offs, csr_src, asb, adb, hh, b2, (float*)d_out, N, 0);
}